// Round 2
// baseline (5854.213 us; speedup 1.0000x reference)
//
#include <hip/hip_runtime.h>

#define NN 50000
#define NE 10000
#define NNZC 200000
#define OBSD 128
#define LATD 256
#define NSTEPS 8

typedef unsigned short u16;
typedef __attribute__((ext_vector_type(8))) short bf16x8;
typedef __attribute__((ext_vector_type(4))) float f32x4;
typedef __attribute__((ext_vector_type(4))) u16 us4;

__device__ __forceinline__ u16 f2b(float f) {
  unsigned int u = __builtin_bit_cast(unsigned int, f);
  u = (u + 0x7FFFu + ((u >> 16) & 1u)) >> 16;
  return (u16)u;
}
__device__ __forceinline__ float b2f(u16 h) {
  unsigned int u = ((unsigned int)h) << 16;
  return __builtin_bit_cast(float, u);
}
__device__ __forceinline__ float fast_tanh(float x) {
  float e = __expf(2.0f * x);
  return 1.0f - 2.0f / (e + 1.0f);
}

typedef __attribute__((address_space(1))) const unsigned int GU32;
typedef __attribute__((address_space(3))) unsigned int LU32;
__device__ __forceinline__ void async16(const void* g, void* l) {
  __builtin_amdgcn_global_load_lds((GU32*)g, (LU32*)l, 16, 0, 0);
}

// ---------------- CSR build ----------------

__global__ void count_kernel(const int* __restrict__ ni, const int* __restrict__ ei,
                             int* __restrict__ cnt_n, int* __restrict__ cnt_e, int nnz) {
  int i = blockIdx.x * blockDim.x + threadIdx.x;
  if (i < nnz) {
    atomicAdd(&cnt_n[ni[i]], 1);
    atomicAdd(&cnt_e[ei[i]], 1);
  }
}

// wave-shuffle scan: ~4 barriers per 1024-chunk (was ~30)
__global__ __launch_bounds__(1024) void scan_kernel(const int* __restrict__ cnt,
                                                    int* __restrict__ off, int* __restrict__ cur,
                                                    float* __restrict__ recip, int n) {
  __shared__ int ws[16];
  __shared__ int carry;
  const int tid = threadIdx.x;
  const int lane = tid & 63, w = tid >> 6;
  if (tid == 0) carry = 0;
  __syncthreads();
  for (int c0 = 0; c0 < n; c0 += 1024) {
    int i = c0 + tid;
    int v = (i < n) ? cnt[i] : 0;
    int s = v;
#pragma unroll
    for (int d = 1; d < 64; d <<= 1) {
      int t2 = __shfl_up(s, d);
      if (lane >= d) s += t2;
    }
    if (lane == 63) ws[w] = s;
    __syncthreads();
    if (w == 0) {
      int x = (lane < 16) ? ws[lane] : 0;
#pragma unroll
      for (int d = 1; d < 16; d <<= 1) {
        int t2 = __shfl_up(x, d);
        if (lane >= d) x += t2;
      }
      if (lane < 16) ws[lane] = x;
    }
    __syncthreads();
    int base = carry + (w ? ws[w - 1] : 0);
    int incl = base + s;
    if (i < n) {
      int ex = incl - v;
      off[i] = ex;
      cur[i] = ex;
      recip[i] = 1.0f / fmaxf((float)v, 1.0f);
    }
    __syncthreads();
    if (tid == 1023) carry += ws[15];
    __syncthreads();
  }
  if (tid == 0) off[n] = carry;
}

__global__ void fill_kernel(const int* __restrict__ ni, const int* __restrict__ ei,
                            int* __restrict__ cur_n, int* __restrict__ cur_e,
                            int* __restrict__ lst_n, int* __restrict__ lst_e, int nnz) {
  int i = blockIdx.x * blockDim.x + threadIdx.x;
  if (i < nnz) {
    int n = ni[i], e = ei[i];
    lst_e[atomicAdd(&cur_e[e], 1)] = n;  // per-edge list of nodes
    lst_n[atomicAdd(&cur_n[n], 1)] = e;  // per-node list of edges
  }
}

// ---------------- small prep ----------------

__global__ void transpose_kernel(const float* __restrict__ W, u16* __restrict__ WT, int K, int N) {
  int i = blockIdx.x * blockDim.x + threadIdx.x;
  if (i >= K * N) return;
  int k = i / N, n = i - k * N;
  WT[n * K + k] = f2b(W[i]);
}

__global__ void to_bf16_kernel(const float* __restrict__ src, u16* __restrict__ dst, int n) {
  int i = (blockIdx.x * blockDim.x + threadIdx.x) * 4;
  if (i >= n) return;
  float4 v = *reinterpret_cast<const float4*>(src + i);
  us4 o;
  o.x = f2b(v.x); o.y = f2b(v.y); o.z = f2b(v.z); o.w = f2b(v.w);
  *reinterpret_cast<us4*>(dst + i) = o;
}

// ---------------- segment mean (one wave per segment), bf16 src ----------------

__global__ __launch_bounds__(256) void agg_kernel(const u16* __restrict__ src,
                                                  const int* __restrict__ off,
                                                  const int* __restrict__ lst,
                                                  const float* __restrict__ recip,
                                                  u16* __restrict__ dst, int nseg) {
  const int lane = threadIdx.x & 63;
  const int seg = (blockIdx.x << 2) + (threadIdx.x >> 6);
  if (seg >= nseg) return;
  const int s = off[seg], e = off[seg + 1];
  float a0 = 0.f, a1 = 0.f, a2 = 0.f, a3 = 0.f;
  for (int p = s; p < e; ++p) {
    int r = lst[p];
    us4 v = *(reinterpret_cast<const us4*>(src + (size_t)r * LATD) + lane);
    a0 += b2f(v.x); a1 += b2f(v.y); a2 += b2f(v.z); a3 += b2f(v.w);
  }
  const float rc = recip[seg];
  us4 o;
  o.x = f2b(a0 * rc); o.y = f2b(a1 * rc); o.z = f2b(a2 * rc); o.w = f2b(a3 * rc);
  *(reinterpret_cast<us4*>(dst + (size_t)seg * LATD) + lane) = o;
}

// ---------------- plain MFMA GEMM (encode / edge-transform / decode) ----------------

enum { EPI_RELU_BF16, EPI_BF16, EPI_F32, EPI_F32_ZT };

template <int MODE>
__global__ __launch_bounds__(256) void gemm_kernel(
    const u16* __restrict__ A, const u16* __restrict__ BT, const float* __restrict__ bias,
    int M, int N, int K,
    u16* __restrict__ outb, float* __restrict__ outf, u16* __restrict__ ztb) {
  __shared__ u16 lA[128 * 32];
  __shared__ u16 lB[128 * 32];
  const int t = threadIdx.x;
  const int m0 = blockIdx.x * 128, n0 = blockIdx.y * 128;
  const int srow = t >> 2;
  const int gslot = (t & 3) ^ ((srow >> 1) & 3);

  int ar0 = m0 + srow;      if (ar0 > M - 1) ar0 = M - 1;
  int ar1 = m0 + srow + 64; if (ar1 > M - 1) ar1 = M - 1;
  const u16* gA0 = A + (size_t)ar0 * K + gslot * 8;
  const u16* gA1 = A + (size_t)ar1 * K + gslot * 8;
  const u16* gB0 = BT + (size_t)(n0 + srow) * K + gslot * 8;
  const u16* gB1 = BT + (size_t)(n0 + srow + 64) * K + gslot * 8;
  char* lAd0 = (char*)lA + t * 16; char* lAd1 = lAd0 + 4096;
  char* lBd0 = (char*)lB + t * 16; char* lBd1 = lBd0 + 4096;

  const int lane = t & 63, wid = t >> 6;
  const int wm = wid >> 1, wn = wid & 1;
  const int lrow = lane & 15, kg = lane >> 4;

  f32x4 acc[4][4] = {};
  const char* lAb = (const char*)lA;
  const char* lBb = (const char*)lB;

  for (int kk = 0; kk < K; kk += 32) {
    async16(gA0 + kk, lAd0);
    async16(gA1 + kk, lAd1);
    async16(gB0 + kk, lBd0);
    async16(gB1 + kk, lBd1);
    __syncthreads();
    bf16x8 af[4], bg[4];
#pragma unroll
    for (int i = 0; i < 4; ++i) {
      int rA = wm * 64 + i * 16 + lrow;
      af[i] = *(const bf16x8*)(lAb + rA * 64 + (((kg ^ (rA >> 1)) & 3) << 4));
      int rB = wn * 64 + i * 16 + lrow;
      bg[i] = *(const bf16x8*)(lBb + rB * 64 + (((kg ^ (rB >> 1)) & 3) << 4));
    }
#pragma unroll
    for (int i = 0; i < 4; ++i)
#pragma unroll
      for (int j = 0; j < 4; ++j)
        acc[i][j] = __builtin_amdgcn_mfma_f32_16x16x32_bf16(af[i], bg[j], acc[i][j], 0, 0, 0);
    __syncthreads();
  }

#pragma unroll
  for (int ti = 0; ti < 4; ++ti) {
    const int grb = m0 + wm * 64 + ti * 16 + (kg << 2);
#pragma unroll
    for (int tj = 0; tj < 4; ++tj) {
      const int gc = n0 + wn * 64 + tj * 16 + lrow;
      const float bv = bias[gc];
#pragma unroll
      for (int j = 0; j < 4; ++j) {
        const int gr = grb + j;
        if (gr >= M) continue;
        float v = acc[ti][tj][j] + bv;
        const size_t idx = (size_t)gr * N + gc;
        if constexpr (MODE == EPI_RELU_BF16) {
          outb[idx] = f2b(fmaxf(v, 0.0f));
        } else if constexpr (MODE == EPI_BF16) {
          outb[idx] = f2b(v);
        } else if constexpr (MODE == EPI_F32) {
          outf[idx] = v;
        } else {  // EPI_F32_ZT
          outf[idx] = v;
          ztb[idx] = f2b(v);
        }
      }
    }
  }
}

// ---------------- fused: agg_n (gather-mean of et) + GEMM(Wen) + RK epilogue ----------------
// Block: 64 M-rows x full N=256, 256 threads (4 waves, wave = one 64-col strip).
// LDS: A 64x256 bf16 (32KB, XOR-swizzled), B double-buffered 256x32 bf16 (2x16KB,
// source-swizzled global_load_lds). Total 64KB -> 2 blocks/CU.

enum { RK_K1, RK_K2, RK_K3, RK_K4 };

template <int MODE>
__global__ __launch_bounds__(256) void fused_gemm50(
    const u16* __restrict__ et, const int* __restrict__ off, const int* __restrict__ lst,
    const float* __restrict__ recip, const u16* __restrict__ BT, const float* __restrict__ bias,
    float* __restrict__ zbuf, u16* __restrict__ accbuf, u16* __restrict__ ztb, float czt) {
  __shared__ u16 lA[64 * 256];
  __shared__ u16 lB[2][256 * 32];
  const int t = threadIdx.x;
  const int lane = t & 63, w = t >> 6;
  const int m0 = blockIdx.x * 64;

  // stage B K-chunk c into buffer buf (pre-swizzled global source, linear LDS dest)
  auto stageB = [&](int c, int buf) {
#pragma unroll
    for (int i = 0; i < 4; ++i) {
      const int seg = i * 4 + w;                 // 16 segments of 1KB
      const int row = seg * 16 + (lane >> 2);    // B row (output col)
      const int sl = lane & 3;                   // 16B slot within row
      const u16* src = BT + (size_t)row * LATD + c * 32 + ((sl ^ ((row >> 1) & 3)) << 3);
      async16(src, (char*)lB[buf] + seg * 1024);
    }
  };

  stageB(0, 0);

  // gather-mean A rows into swizzled LDS: wave w handles rows w*16..w*16+15
  for (int rr = 0; rr < 16; ++rr) {
    const int r = w * 16 + rr;
    const int gr = m0 + r;
    float a0 = 0.f, a1 = 0.f, a2 = 0.f, a3 = 0.f;
    if (gr < NN) {
      const int s = off[gr], e = off[gr + 1];
      for (int p = s; p < e; ++p) {
        int er = lst[p];
        us4 v = *(reinterpret_cast<const us4*>(et + (size_t)er * LATD) + lane);
        a0 += b2f(v.x); a1 += b2f(v.y); a2 += b2f(v.z); a3 += b2f(v.w);
      }
      const float rc = recip[gr];
      a0 *= rc; a1 *= rc; a2 *= rc; a3 *= rc;
    }
    us4 o;
    o.x = f2b(a0); o.y = f2b(a1); o.z = f2b(a2); o.w = f2b(a3);
    const int boff = r * 512 + ((((lane >> 1) ^ (r & 7)) << 4) | ((lane & 1) << 3));
    *(us4*)((char*)lA + boff) = o;
  }

  __syncthreads();  // A + B chunk 0 resident

  const int lrow = lane & 15, kg = lane >> 4;
  f32x4 acc[4][4] = {};

  for (int c = 0; c < 8; ++c) {
    const int cur = c & 1;
    if (c < 7) stageB(c + 1, cur ^ 1);
    bf16x8 af[4], bg[4];
#pragma unroll
    for (int i = 0; i < 4; ++i) {
      const int rA = i * 16 + lrow;
      const int ks = c * 4 + kg;
      af[i] = *(const bf16x8*)((const char*)lA + rA * 512 + ((ks ^ (rA & 7)) << 4));
      const int rB = w * 64 + i * 16 + lrow;
      bg[i] = *(const bf16x8*)((const char*)lB[cur] + rB * 64 + ((kg ^ ((rB >> 1) & 3)) << 4));
    }
#pragma unroll
    for (int i = 0; i < 4; ++i)
#pragma unroll
      for (int j = 0; j < 4; ++j)
        acc[i][j] = __builtin_amdgcn_mfma_f32_16x16x32_bf16(af[i], bg[j], acc[i][j], 0, 0, 0);
    __syncthreads();
  }

  const float dt6 = 0.125f / 6.0f;
#pragma unroll
  for (int ti = 0; ti < 4; ++ti) {
    const int grb = m0 + ti * 16 + (kg << 2);
#pragma unroll
    for (int tj = 0; tj < 4; ++tj) {
      const int gc = w * 64 + tj * 16 + lrow;
      const float bv = bias[gc];
#pragma unroll
      for (int j = 0; j < 4; ++j) {
        const int gr = grb + j;
        if (gr >= NN) continue;
        const float v = acc[ti][tj][j] + bv;
        const size_t idx = (size_t)gr * LATD + gc;
        const float kv = fast_tanh(v);
        if constexpr (MODE == RK_K1) {
          accbuf[idx] = f2b(kv);
          ztb[idx] = f2b(zbuf[idx] + czt * kv);
        } else if constexpr (MODE == RK_K2 || MODE == RK_K3) {
          accbuf[idx] = f2b(b2f(accbuf[idx]) + 2.0f * kv);
          ztb[idx] = f2b(zbuf[idx] + czt * kv);
        } else {  // RK_K4
          const float zn = zbuf[idx] + dt6 * (b2f(accbuf[idx]) + kv);
          zbuf[idx] = zn;
          ztb[idx] = f2b(zn);
        }
      }
    }
  }
}

// ---------------- launch ----------------

extern "C" void kernel_launch(void* const* d_in, const int* in_sizes, int n_in,
                              void* d_out, int out_size, void* d_ws, size_t ws_size,
                              hipStream_t stream) {
  const float* X = (const float*)d_in[0];
  const float* encW0 = (const float*)d_in[1];
  const float* encb0 = (const float*)d_in[2];
  const float* encW1 = (const float*)d_in[3];
  const float* encb1 = (const float*)d_in[4];
  const float* Wne = (const float*)d_in[5];
  const float* bne = (const float*)d_in[6];
  const float* Wen = (const float*)d_in[7];
  const float* ben = (const float*)d_in[8];
  const float* decW0 = (const float*)d_in[9];
  const float* decb0 = (const float*)d_in[10];
  const float* decW1 = (const float*)d_in[11];
  const float* decb1 = (const float*)d_in[12];
  const int* node_idx = (const int*)d_in[13];
  const int* edge_idx = (const int*)d_in[14];
  float* out = (float*)d_out;

  char* p = (char*)d_ws;
  auto alloc = [&](size_t bytes) {
    char* r = p;
    p += (bytes + 255) & ~(size_t)255;
    return r;
  };
  float* z      = (float*)alloc((size_t)NN * LATD * 4);
  u16* accb     = (u16*)alloc((size_t)NN * LATD * 2);
  u16* zt       = (u16*)alloc((size_t)NN * LATD * 2);
  u16* mh       = (u16*)alloc((size_t)NN * LATD * 2);
  u16* eagg     = (u16*)alloc((size_t)NE * LATD * 2);
  u16* et       = (u16*)alloc((size_t)NE * LATD * 2);
  u16* encW0T   = (u16*)alloc((size_t)OBSD * LATD * 2);
  u16* encW1T   = (u16*)alloc((size_t)LATD * LATD * 2);
  u16* WneT     = (u16*)alloc((size_t)LATD * LATD * 2);
  u16* WenT     = (u16*)alloc((size_t)LATD * LATD * 2);
  u16* decW0T   = (u16*)alloc((size_t)LATD * LATD * 2);
  u16* decW1T   = (u16*)alloc((size_t)LATD * OBSD * 2);
  int* cnt      = (int*)alloc((size_t)(NE + NN) * 4);
  int* cnt_e = cnt; int* cnt_n = cnt + NE;
  int* off_e    = (int*)alloc((size_t)(NE + 1) * 4);
  int* off_n    = (int*)alloc((size_t)(NN + 1) * 4);
  int* cur_e    = (int*)alloc((size_t)NE * 4);
  int* cur_n    = (int*)alloc((size_t)NN * 4);
  int* lst_e    = (int*)alloc((size_t)NNZC * 4);
  int* lst_n    = (int*)alloc((size_t)NNZC * 4);
  float* recip_e = (float*)alloc((size_t)NE * 4);
  float* recip_n = (float*)alloc((size_t)NN * 4);

  size_t needed = (size_t)(p - (char*)d_ws);
  if (needed > ws_size) {
    hipMemsetAsync(d_out, 0x7F, (size_t)out_size * 4, stream);
    return;
  }

  // CSR build
  hipMemsetAsync(cnt, 0, (size_t)(NE + NN) * 4, stream);
  count_kernel<<<(NNZC + 255) / 256, 256, 0, stream>>>(node_idx, edge_idx, cnt_n, cnt_e, NNZC);
  scan_kernel<<<1, 1024, 0, stream>>>(cnt_e, off_e, cur_e, recip_e, NE);
  scan_kernel<<<1, 1024, 0, stream>>>(cnt_n, off_n, cur_n, recip_n, NN);
  fill_kernel<<<(NNZC + 255) / 256, 256, 0, stream>>>(node_idx, edge_idx, cur_n, cur_e, lst_n, lst_e, NNZC);

  // weight prep
  transpose_kernel<<<(OBSD * LATD + 255) / 256, 256, 0, stream>>>(encW0, encW0T, OBSD, LATD);
  transpose_kernel<<<(LATD * LATD + 255) / 256, 256, 0, stream>>>(encW1, encW1T, LATD, LATD);
  transpose_kernel<<<(LATD * LATD + 255) / 256, 256, 0, stream>>>(Wne, WneT, LATD, LATD);
  transpose_kernel<<<(LATD * LATD + 255) / 256, 256, 0, stream>>>(Wen, WenT, LATD, LATD);
  transpose_kernel<<<(LATD * LATD + 255) / 256, 256, 0, stream>>>(decW0, decW0T, LATD, LATD);
  transpose_kernel<<<(LATD * OBSD + 255) / 256, 256, 0, stream>>>(decW1, decW1T, LATD, OBSD);

  const dim3 blk(256);
  const dim3 g50((NN + 127) / 128, LATD / 128);   // (391, 2)
  const dim3 g10((NE + 127) / 128, LATD / 128);   // (79, 2)
  const dim3 gdec((NN + 127) / 128, OBSD / 128);  // (391, 1)
  const dim3 gf((NN + 63) / 64);                  // 782

  // encode: h1 = relu(X@W0+b0) ; z = h1@W1+b1 (f32 + bf16 shadow)
  to_bf16_kernel<<<(NN * OBSD / 4 + 255) / 256, 256, 0, stream>>>(X, zt, NN * OBSD);
  gemm_kernel<EPI_RELU_BF16><<<g50, blk, 0, stream>>>(zt, encW0T, encb0, NN, LATD, OBSD,
                                                      mh, nullptr, nullptr);
  gemm_kernel<EPI_F32_ZT><<<g50, blk, 0, stream>>>(mh, encW1T, encb1, NN, LATD, LATD,
                                                   nullptr, z, zt);

  // RK4 steps: 3 kernels per substep
  for (int s = 0; s < NSTEPS; ++s) {
    for (int k = 0; k < 4; ++k) {
      agg_kernel<<<(NE + 3) / 4, blk, 0, stream>>>(zt, off_e, lst_e, recip_e, eagg, NE);
      gemm_kernel<EPI_BF16><<<g10, blk, 0, stream>>>(eagg, WneT, bne, NE, LATD, LATD,
                                                     et, nullptr, nullptr);
      if (k == 0)
        fused_gemm50<RK_K1><<<gf, blk, 0, stream>>>(et, off_n, lst_n, recip_n, WenT, ben,
                                                    z, accb, zt, 0.0625f);
      else if (k == 1)
        fused_gemm50<RK_K2><<<gf, blk, 0, stream>>>(et, off_n, lst_n, recip_n, WenT, ben,
                                                    z, accb, zt, 0.0625f);
      else if (k == 2)
        fused_gemm50<RK_K3><<<gf, blk, 0, stream>>>(et, off_n, lst_n, recip_n, WenT, ben,
                                                    z, accb, zt, 0.125f);
      else
        fused_gemm50<RK_K4><<<gf, blk, 0, stream>>>(et, off_n, lst_n, recip_n, WenT, ben,
                                                    z, accb, zt, 0.f);
    }
  }

  // decode (zt already holds bf16(z) from K4)
  gemm_kernel<EPI_RELU_BF16><<<g50, blk, 0, stream>>>(zt, decW0T, decb0, NN, LATD, LATD,
                                                      mh, nullptr, nullptr);
  gemm_kernel<EPI_F32><<<gdec, blk, 0, stream>>>(mh, decW1T, decb1, NN, OBSD, LATD,
                                                 nullptr, out, nullptr);
}

// Round 3
// 3685.522 us; speedup vs baseline: 1.5884x; 1.5884x over previous
//
#include <hip/hip_runtime.h>

#define NN 50000
#define NE 10000
#define NNZC 200000
#define OBSD 128
#define LATD 256
#define NSTEPS 8

typedef unsigned short u16;
typedef __attribute__((ext_vector_type(8))) short bf16x8;
typedef __attribute__((ext_vector_type(4))) float f32x4;
typedef __attribute__((ext_vector_type(4))) u16 us4;
typedef __attribute__((ext_vector_type(8))) u16 us8;

__device__ __forceinline__ u16 f2b(float f) {
  unsigned int u = __builtin_bit_cast(unsigned int, f);
  u = (u + 0x7FFFu + ((u >> 16) & 1u)) >> 16;
  return (u16)u;
}
__device__ __forceinline__ float b2f(u16 h) {
  unsigned int u = ((unsigned int)h) << 16;
  return __builtin_bit_cast(float, u);
}
__device__ __forceinline__ float fast_tanh(float x) {
  float e = __expf(2.0f * x);
  return 1.0f - 2.0f / (e + 1.0f);
}

typedef __attribute__((address_space(1))) const unsigned int GU32;
typedef __attribute__((address_space(3))) unsigned int LU32;
__device__ __forceinline__ void async16(const void* g, void* l) {
  __builtin_amdgcn_global_load_lds((GU32*)g, (LU32*)l, 16, 0, 0);
}

// ---------------- CSR build ----------------

__global__ void count_kernel(const int* __restrict__ ni, const int* __restrict__ ei,
                             int* __restrict__ cnt_n, int* __restrict__ cnt_e, int nnz) {
  int i = blockIdx.x * blockDim.x + threadIdx.x;
  if (i < nnz) {
    atomicAdd(&cnt_n[ni[i]], 1);
    atomicAdd(&cnt_e[ei[i]], 1);
  }
}

__global__ __launch_bounds__(1024) void scan_kernel(const int* __restrict__ cnt,
                                                    int* __restrict__ off, int* __restrict__ cur,
                                                    float* __restrict__ recip, int n) {
  __shared__ int ws[16];
  __shared__ int carry;
  const int tid = threadIdx.x;
  const int lane = tid & 63, w = tid >> 6;
  if (tid == 0) carry = 0;
  __syncthreads();
  for (int c0 = 0; c0 < n; c0 += 1024) {
    int i = c0 + tid;
    int v = (i < n) ? cnt[i] : 0;
    int s = v;
#pragma unroll
    for (int d = 1; d < 64; d <<= 1) {
      int t2 = __shfl_up(s, d);
      if (lane >= d) s += t2;
    }
    if (lane == 63) ws[w] = s;
    __syncthreads();
    if (w == 0) {
      int x = (lane < 16) ? ws[lane] : 0;
#pragma unroll
      for (int d = 1; d < 16; d <<= 1) {
        int t2 = __shfl_up(x, d);
        if (lane >= d) x += t2;
      }
      if (lane < 16) ws[lane] = x;
    }
    __syncthreads();
    int base = carry + (w ? ws[w - 1] : 0);
    int incl = base + s;
    if (i < n) {
      int ex = incl - v;
      off[i] = ex;
      cur[i] = ex;
      recip[i] = 1.0f / fmaxf((float)v, 1.0f);
    }
    __syncthreads();
    if (tid == 1023) carry += ws[15];
    __syncthreads();
  }
  if (tid == 0) off[n] = carry;
}

__global__ void fill_kernel(const int* __restrict__ ni, const int* __restrict__ ei,
                            int* __restrict__ cur_n, int* __restrict__ cur_e,
                            int* __restrict__ lst_n, int* __restrict__ lst_e, int nnz) {
  int i = blockIdx.x * blockDim.x + threadIdx.x;
  if (i < nnz) {
    int n = ni[i], e = ei[i];
    lst_e[atomicAdd(&cur_e[e], 1)] = n;
    lst_n[atomicAdd(&cur_n[n], 1)] = e;
  }
}

// ---------------- small prep ----------------

__global__ void transpose_kernel(const float* __restrict__ W, u16* __restrict__ WT, int K, int N) {
  int i = blockIdx.x * blockDim.x + threadIdx.x;
  if (i >= K * N) return;
  int k = i / N, n = i - k * N;
  WT[n * K + k] = f2b(W[i]);
}

__global__ void to_bf16_kernel(const float* __restrict__ src, u16* __restrict__ dst, int n) {
  int i = (blockIdx.x * blockDim.x + threadIdx.x) * 4;
  if (i >= n) return;
  float4 v = *reinterpret_cast<const float4*>(src + i);
  us4 o;
  o.x = f2b(v.x); o.y = f2b(v.y); o.z = f2b(v.z); o.w = f2b(v.w);
  *reinterpret_cast<us4*>(dst + i) = o;
}

// ---------------- segment mean (one wave per segment), bf16 src ----------------

__global__ __launch_bounds__(256) void agg_kernel(const u16* __restrict__ src,
                                                  const int* __restrict__ off,
                                                  const int* __restrict__ lst,
                                                  const float* __restrict__ recip,
                                                  u16* __restrict__ dst, int nseg) {
  const int lane = threadIdx.x & 63;
  const int seg = (blockIdx.x << 2) + (threadIdx.x >> 6);
  if (seg >= nseg) return;
  const int s = off[seg], e = off[seg + 1];
  float a0 = 0.f, a1 = 0.f, a2 = 0.f, a3 = 0.f;
  for (int p = s; p < e; ++p) {
    int r = lst[p];
    us4 v = *(reinterpret_cast<const us4*>(src + (size_t)r * LATD) + lane);
    a0 += b2f(v.x); a1 += b2f(v.y); a2 += b2f(v.z); a3 += b2f(v.w);
  }
  const float rc = recip[seg];
  us4 o;
  o.x = f2b(a0 * rc); o.y = f2b(a1 * rc); o.z = f2b(a2 * rc); o.w = f2b(a3 * rc);
  *(reinterpret_cast<us4*>(dst + (size_t)seg * LATD) + lane) = o;
}

// ---------------- MFMA GEMM with LDS-staged coalesced epilogue ----------------
// C = A[MxK](bf16) * BT[NxK]^T(bf16) + bias, 128x128 tile, 4 waves.
// Epilogue: each wave stages its 16x64 C-stripe in private padded LDS
// (stride 66 f32), re-reads row-major so all global stores are 16B-coalesced.

enum { EPI_RELU_BF16, EPI_BF16, EPI_F32, EPI_F32_ZT, EPI_K1, EPI_K2, EPI_K3, EPI_K4 };

template <int MODE>
__global__ __launch_bounds__(256) void gemm_kernel(
    const u16* __restrict__ A, const u16* __restrict__ BT, const float* __restrict__ bias,
    int M, int N, int K,
    u16* __restrict__ outb, float* __restrict__ outf,
    float* __restrict__ zbuf, u16* __restrict__ accbuf, u16* __restrict__ ztb, float czt) {
  __shared__ char smem[4 * 16 * 66 * 4];  // 16896B; GEMM phase uses first 16KB
  u16* lA = (u16*)smem;
  u16* lB = (u16*)(smem + 8192);
  const int t = threadIdx.x;
  const int m0 = blockIdx.x * 128, n0 = blockIdx.y * 128;
  const int srow = t >> 2;
  const int gslot = (t & 3) ^ ((srow >> 1) & 3);

  int ar0 = m0 + srow;      if (ar0 > M - 1) ar0 = M - 1;
  int ar1 = m0 + srow + 64; if (ar1 > M - 1) ar1 = M - 1;
  const u16* gA0 = A + (size_t)ar0 * K + gslot * 8;
  const u16* gA1 = A + (size_t)ar1 * K + gslot * 8;
  const u16* gB0 = BT + (size_t)(n0 + srow) * K + gslot * 8;
  const u16* gB1 = BT + (size_t)(n0 + srow + 64) * K + gslot * 8;
  char* lAd0 = (char*)lA + t * 16; char* lAd1 = lAd0 + 4096;
  char* lBd0 = (char*)lB + t * 16; char* lBd1 = lBd0 + 4096;

  const int lane = t & 63, wid = t >> 6;
  const int wm = wid >> 1, wn = wid & 1;
  const int lrow = lane & 15, kg = lane >> 4;

  f32x4 acc[4][4] = {};
  const char* lAb = (const char*)lA;
  const char* lBb = (const char*)lB;

  for (int kk = 0; kk < K; kk += 32) {
    async16(gA0 + kk, lAd0);
    async16(gA1 + kk, lAd1);
    async16(gB0 + kk, lBd0);
    async16(gB1 + kk, lBd1);
    __syncthreads();
    bf16x8 af[4], bg[4];
#pragma unroll
    for (int i = 0; i < 4; ++i) {
      int rA = wm * 64 + i * 16 + lrow;
      af[i] = *(const bf16x8*)(lAb + rA * 64 + (((kg ^ (rA >> 1)) & 3) << 4));
      int rB = wn * 64 + i * 16 + lrow;
      bg[i] = *(const bf16x8*)(lBb + rB * 64 + (((kg ^ (rB >> 1)) & 3) << 4));
    }
#pragma unroll
    for (int i = 0; i < 4; ++i)
#pragma unroll
      for (int j = 0; j < 4; ++j)
        acc[i][j] = __builtin_amdgcn_mfma_f32_16x16x32_bf16(af[i], bg[j], acc[i][j], 0, 0, 0);
    __syncthreads();
  }

  // ---- staged epilogue (wave-private LDS region; no barriers needed) ----
  float* stage = (float*)smem + wid * (16 * 66);
  const int rr = lane >> 3;        // row within 8-row pass
  const int c0 = (lane & 7) * 8;   // col octet
  const float dt6 = 0.125f / 6.0f;

#pragma unroll
  for (int ti = 0; ti < 4; ++ti) {
    // write C stripe (16 rows x 64 cols) + bias into LDS
#pragma unroll
    for (int tj = 0; tj < 4; ++tj) {
      const float bv = bias[n0 + wn * 64 + tj * 16 + lrow];
#pragma unroll
      for (int j = 0; j < 4; ++j)
        stage[(kg * 4 + j) * 66 + tj * 16 + lrow] = acc[ti][tj][j] + bv;
    }
    // read back row-major; 8 lanes/row -> 16B stores, fully coalesced
#pragma unroll
    for (int pass = 0; pass < 2; ++pass) {
      const int r = pass * 8 + rr;
      const int gr = m0 + wm * 64 + ti * 16 + r;
      if (gr >= M) continue;
      const int gc = n0 + wn * 64 + c0;
      const size_t idx = (size_t)gr * N + gc;
      float v[8];
      *(float4*)v = *(const float4*)&stage[r * 66 + c0];
      *(float4*)(v + 4) = *(const float4*)&stage[r * 66 + c0 + 4];

      if constexpr (MODE == EPI_RELU_BF16 || MODE == EPI_BF16) {
        us8 o;
#pragma unroll
        for (int e2 = 0; e2 < 8; ++e2)
          o[e2] = f2b(MODE == EPI_RELU_BF16 ? fmaxf(v[e2], 0.0f) : v[e2]);
        *(us8*)(outb + idx) = o;
      } else if constexpr (MODE == EPI_F32 || MODE == EPI_F32_ZT) {
        *(float4*)(outf + idx) = *(float4*)v;
        *(float4*)(outf + idx + 4) = *(float4*)(v + 4);
        if constexpr (MODE == EPI_F32_ZT) {
          us8 o;
#pragma unroll
          for (int e2 = 0; e2 < 8; ++e2) o[e2] = f2b(v[e2]);
          *(us8*)(ztb + idx) = o;
        }
      } else {
        // RK modes
        float kv[8];
#pragma unroll
        for (int e2 = 0; e2 < 8; ++e2) kv[e2] = fast_tanh(v[e2]);
        if constexpr (MODE == EPI_K1) {
          us8 ao, zo;
          float4 z0 = *(const float4*)(zbuf + idx);
          float4 z1 = *(const float4*)(zbuf + idx + 4);
          const float* zp = (const float*)&z0;
#pragma unroll
          for (int e2 = 0; e2 < 8; ++e2) {
            float zv = (e2 < 4) ? ((const float*)&z0)[e2] : ((const float*)&z1)[e2 - 4];
            ao[e2] = f2b(kv[e2]);
            zo[e2] = f2b(zv + czt * kv[e2]);
          }
          (void)zp;
          *(us8*)(accbuf + idx) = ao;
          *(us8*)(ztb + idx) = zo;
        } else if constexpr (MODE == EPI_K2 || MODE == EPI_K3) {
          us8 av = *(const us8*)(accbuf + idx);
          float4 z0 = *(const float4*)(zbuf + idx);
          float4 z1 = *(const float4*)(zbuf + idx + 4);
          us8 ao, zo;
#pragma unroll
          for (int e2 = 0; e2 < 8; ++e2) {
            float zv = (e2 < 4) ? ((const float*)&z0)[e2] : ((const float*)&z1)[e2 - 4];
            ao[e2] = f2b(b2f(av[e2]) + 2.0f * kv[e2]);
            zo[e2] = f2b(zv + czt * kv[e2]);
          }
          *(us8*)(accbuf + idx) = ao;
          *(us8*)(ztb + idx) = zo;
        } else {  // EPI_K4
          us8 av = *(const us8*)(accbuf + idx);
          float4 z0 = *(const float4*)(zbuf + idx);
          float4 z1 = *(const float4*)(zbuf + idx + 4);
          float zn[8];
          us8 zo;
#pragma unroll
          for (int e2 = 0; e2 < 8; ++e2) {
            float zv = (e2 < 4) ? ((const float*)&z0)[e2] : ((const float*)&z1)[e2 - 4];
            zn[e2] = zv + dt6 * (b2f(av[e2]) + kv[e2]);
            zo[e2] = f2b(zn[e2]);
          }
          *(float4*)(zbuf + idx) = *(float4*)zn;
          *(float4*)(zbuf + idx + 4) = *(float4*)(zn + 4);
          *(us8*)(ztb + idx) = zo;
        }
      }
    }
  }
}

// ---------------- launch ----------------

extern "C" void kernel_launch(void* const* d_in, const int* in_sizes, int n_in,
                              void* d_out, int out_size, void* d_ws, size_t ws_size,
                              hipStream_t stream) {
  const float* X = (const float*)d_in[0];
  const float* encW0 = (const float*)d_in[1];
  const float* encb0 = (const float*)d_in[2];
  const float* encW1 = (const float*)d_in[3];
  const float* encb1 = (const float*)d_in[4];
  const float* Wne = (const float*)d_in[5];
  const float* bne = (const float*)d_in[6];
  const float* Wen = (const float*)d_in[7];
  const float* ben = (const float*)d_in[8];
  const float* decW0 = (const float*)d_in[9];
  const float* decb0 = (const float*)d_in[10];
  const float* decW1 = (const float*)d_in[11];
  const float* decb1 = (const float*)d_in[12];
  const int* node_idx = (const int*)d_in[13];
  const int* edge_idx = (const int*)d_in[14];
  float* out = (float*)d_out;

  char* p = (char*)d_ws;
  auto alloc = [&](size_t bytes) {
    char* r = p;
    p += (bytes + 255) & ~(size_t)255;
    return r;
  };
  float* z      = (float*)alloc((size_t)NN * LATD * 4);
  u16* accb     = (u16*)alloc((size_t)NN * LATD * 2);
  u16* zt       = (u16*)alloc((size_t)NN * LATD * 2);
  u16* mh       = (u16*)alloc((size_t)NN * LATD * 2);
  u16* eagg     = (u16*)alloc((size_t)NE * LATD * 2);
  u16* et       = (u16*)alloc((size_t)NE * LATD * 2);
  u16* encW0T   = (u16*)alloc((size_t)OBSD * LATD * 2);
  u16* encW1T   = (u16*)alloc((size_t)LATD * LATD * 2);
  u16* WneT     = (u16*)alloc((size_t)LATD * LATD * 2);
  u16* WenT     = (u16*)alloc((size_t)LATD * LATD * 2);
  u16* decW0T   = (u16*)alloc((size_t)LATD * LATD * 2);
  u16* decW1T   = (u16*)alloc((size_t)LATD * OBSD * 2);
  int* cnt      = (int*)alloc((size_t)(NE + NN) * 4);
  int* cnt_e = cnt; int* cnt_n = cnt + NE;
  int* off_e    = (int*)alloc((size_t)(NE + 1) * 4);
  int* off_n    = (int*)alloc((size_t)(NN + 1) * 4);
  int* cur_e    = (int*)alloc((size_t)NE * 4);
  int* cur_n    = (int*)alloc((size_t)NN * 4);
  int* lst_e    = (int*)alloc((size_t)NNZC * 4);
  int* lst_n    = (int*)alloc((size_t)NNZC * 4);
  float* recip_e = (float*)alloc((size_t)NE * 4);
  float* recip_n = (float*)alloc((size_t)NN * 4);

  size_t needed = (size_t)(p - (char*)d_ws);
  if (needed > ws_size) {
    hipMemsetAsync(d_out, 0x7F, (size_t)out_size * 4, stream);
    return;
  }

  // CSR build
  hipMemsetAsync(cnt, 0, (size_t)(NE + NN) * 4, stream);
  count_kernel<<<(NNZC + 255) / 256, 256, 0, stream>>>(node_idx, edge_idx, cnt_n, cnt_e, NNZC);
  scan_kernel<<<1, 1024, 0, stream>>>(cnt_e, off_e, cur_e, recip_e, NE);
  scan_kernel<<<1, 1024, 0, stream>>>(cnt_n, off_n, cur_n, recip_n, NN);
  fill_kernel<<<(NNZC + 255) / 256, 256, 0, stream>>>(node_idx, edge_idx, cur_n, cur_e, lst_n, lst_e, NNZC);

  // weight prep
  transpose_kernel<<<(OBSD * LATD + 255) / 256, 256, 0, stream>>>(encW0, encW0T, OBSD, LATD);
  transpose_kernel<<<(LATD * LATD + 255) / 256, 256, 0, stream>>>(encW1, encW1T, LATD, LATD);
  transpose_kernel<<<(LATD * LATD + 255) / 256, 256, 0, stream>>>(Wne, WneT, LATD, LATD);
  transpose_kernel<<<(LATD * LATD + 255) / 256, 256, 0, stream>>>(Wen, WenT, LATD, LATD);
  transpose_kernel<<<(LATD * LATD + 255) / 256, 256, 0, stream>>>(decW0, decW0T, LATD, LATD);
  transpose_kernel<<<(LATD * OBSD + 255) / 256, 256, 0, stream>>>(decW1, decW1T, LATD, OBSD);

  const dim3 blk(256);
  const dim3 g50((NN + 127) / 128, LATD / 128);   // (391, 2)
  const dim3 g10((NE + 127) / 128, LATD / 128);   // (79, 2)
  const dim3 gdec((NN + 127) / 128, OBSD / 128);  // (391, 1)

  // encode
  to_bf16_kernel<<<(NN * OBSD / 4 + 255) / 256, 256, 0, stream>>>(X, zt, NN * OBSD);
  gemm_kernel<EPI_RELU_BF16><<<g50, blk, 0, stream>>>(zt, encW0T, encb0, NN, LATD, OBSD,
                                                      mh, nullptr, nullptr, nullptr, nullptr, 0.f);
  gemm_kernel<EPI_F32_ZT><<<g50, blk, 0, stream>>>(mh, encW1T, encb1, NN, LATD, LATD,
                                                   nullptr, z, nullptr, nullptr, zt, 0.f);

  // RK4 steps: 4 kernels per substep
  for (int s = 0; s < NSTEPS; ++s) {
    for (int k = 0; k < 4; ++k) {
      agg_kernel<<<(NE + 3) / 4, blk, 0, stream>>>(zt, off_e, lst_e, recip_e, eagg, NE);
      gemm_kernel<EPI_BF16><<<g10, blk, 0, stream>>>(eagg, WneT, bne, NE, LATD, LATD,
                                                     et, nullptr, nullptr, nullptr, nullptr, 0.f);
      agg_kernel<<<(NN + 3) / 4, blk, 0, stream>>>(et, off_n, lst_n, recip_n, mh, NN);
      if (k == 0)
        gemm_kernel<EPI_K1><<<g50, blk, 0, stream>>>(mh, WenT, ben, NN, LATD, LATD,
                                                     nullptr, nullptr, z, accb, zt, 0.0625f);
      else if (k == 1)
        gemm_kernel<EPI_K2><<<g50, blk, 0, stream>>>(mh, WenT, ben, NN, LATD, LATD,
                                                     nullptr, nullptr, z, accb, zt, 0.0625f);
      else if (k == 2)
        gemm_kernel<EPI_K3><<<g50, blk, 0, stream>>>(mh, WenT, ben, NN, LATD, LATD,
                                                     nullptr, nullptr, z, accb, zt, 0.125f);
      else
        gemm_kernel<EPI_K4><<<g50, blk, 0, stream>>>(mh, WenT, ben, NN, LATD, LATD,
                                                     nullptr, nullptr, z, accb, zt, 0.f);
    }
  }

  // decode (zt holds bf16(z) from K4)
  gemm_kernel<EPI_RELU_BF16><<<g50, blk, 0, stream>>>(zt, decW0T, decb0, NN, LATD, LATD,
                                                      mh, nullptr, nullptr, nullptr, nullptr, 0.f);
  gemm_kernel<EPI_F32><<<gdec, blk, 0, stream>>>(mh, decW1T, decb1, NN, OBSD, LATD,
                                                 nullptr, out, nullptr, nullptr, nullptr, 0.f);
}

// Round 4
// 3292.102 us; speedup vs baseline: 1.7783x; 1.1195x over previous
//
#include <hip/hip_runtime.h>

#define NN 50000
#define NE 10000
#define NNZC 200000
#define OBSD 128
#define LATD 256
#define NSTEPS 8

typedef unsigned short u16;
typedef __attribute__((ext_vector_type(8))) short bf16x8;
typedef __attribute__((ext_vector_type(4))) float f32x4;
typedef __attribute__((ext_vector_type(4))) u16 us4;
typedef __attribute__((ext_vector_type(8))) u16 us8;

__device__ __forceinline__ u16 f2b(float f) {
  unsigned int u = __builtin_bit_cast(unsigned int, f);
  u = (u + 0x7FFFu + ((u >> 16) & 1u)) >> 16;
  return (u16)u;
}
__device__ __forceinline__ float b2f(u16 h) {
  unsigned int u = ((unsigned int)h) << 16;
  return __builtin_bit_cast(float, u);
}
__device__ __forceinline__ float fast_tanh(float x) {
  float e = __expf(2.0f * x);
  return 1.0f - 2.0f / (e + 1.0f);
}

typedef __attribute__((address_space(1))) const unsigned int GU32;
typedef __attribute__((address_space(3))) unsigned int LU32;
__device__ __forceinline__ void async16(const void* g, void* l) {
  __builtin_amdgcn_global_load_lds((GU32*)g, (LU32*)l, 16, 0, 0);
}

// ---------------- CSR build ----------------

__global__ void count_kernel(const int* __restrict__ ni, const int* __restrict__ ei,
                             int* __restrict__ cnt_n, int* __restrict__ cnt_e, int nnz) {
  int i = blockIdx.x * blockDim.x + threadIdx.x;
  if (i < nnz) {
    atomicAdd(&cnt_n[ni[i]], 1);
    atomicAdd(&cnt_e[ei[i]], 1);
  }
}

// phase 1: per-block (1024) local exclusive scan -> off, block totals -> bsum
__global__ __launch_bounds__(1024) void scan1_kernel(const int* __restrict__ cnt,
                                                     int* __restrict__ off,
                                                     int* __restrict__ bsum, int n) {
  __shared__ int ws[16];
  const int tid = threadIdx.x;
  const int lane = tid & 63, w = tid >> 6;
  const int i = blockIdx.x * 1024 + tid;
  int v = (i < n) ? cnt[i] : 0;
  int s = v;
#pragma unroll
  for (int d = 1; d < 64; d <<= 1) {
    int t2 = __shfl_up(s, d);
    if (lane >= d) s += t2;
  }
  if (lane == 63) ws[w] = s;
  __syncthreads();
  if (w == 0) {
    int x = (lane < 16) ? ws[lane] : 0;
#pragma unroll
    for (int d = 1; d < 16; d <<= 1) {
      int t2 = __shfl_up(x, d);
      if (lane >= d) x += t2;
    }
    if (lane < 16) ws[lane] = x;
  }
  __syncthreads();
  const int base = w ? ws[w - 1] : 0;
  if (i < n) off[i] = base + s - v;
  if (tid == 0) bsum[blockIdx.x] = ws[15];
}

// phase 2: single-wave exclusive scan of block sums (nb <= 64); total -> bsum[nb]
__global__ void scan2_kernel(int* __restrict__ bsum, int nb) {
  const int lane = threadIdx.x;
  int v = (lane < nb) ? bsum[lane] : 0;
  int s = v;
#pragma unroll
  for (int d = 1; d < 64; d <<= 1) {
    int t2 = __shfl_up(s, d);
    if (lane >= d) s += t2;
  }
  if (lane < nb) bsum[lane] = s - v;
  if (lane == 63) bsum[nb] = s;
}

// phase 3: add block prefix; produce cur & recip; off[n] = total
__global__ void scan3_kernel(const int* __restrict__ cnt, int* __restrict__ off,
                             int* __restrict__ cur, float* __restrict__ recip,
                             const int* __restrict__ bsum, int n) {
  const int i = blockIdx.x * blockDim.x + threadIdx.x;
  if (i < n) {
    const int o = off[i] + bsum[i >> 10];
    off[i] = o;
    cur[i] = o;
    recip[i] = 1.0f / fmaxf((float)cnt[i], 1.0f);
  }
  if (i == 0) off[n] = bsum[(n + 1023) >> 10];
}

__global__ void fill_kernel(const int* __restrict__ ni, const int* __restrict__ ei,
                            int* __restrict__ cur_n, int* __restrict__ cur_e,
                            int* __restrict__ lst_n, int* __restrict__ lst_e, int nnz) {
  int i = blockIdx.x * blockDim.x + threadIdx.x;
  if (i < nnz) {
    int n = ni[i], e = ei[i];
    lst_e[atomicAdd(&cur_e[e], 1)] = n;
    lst_n[atomicAdd(&cur_n[n], 1)] = e;
  }
}

// ---------------- small prep ----------------

__global__ void transpose_kernel(const float* __restrict__ W, u16* __restrict__ WT, int K, int N) {
  int i = blockIdx.x * blockDim.x + threadIdx.x;
  if (i >= K * N) return;
  int k = i / N, n = i - k * N;
  WT[n * K + k] = f2b(W[i]);
}

__global__ void to_bf16_kernel(const float* __restrict__ src, u16* __restrict__ dst, int n) {
  int i = (blockIdx.x * blockDim.x + threadIdx.x) * 4;
  if (i >= n) return;
  float4 v = *reinterpret_cast<const float4*>(src + i);
  us4 o;
  o.x = f2b(v.x); o.y = f2b(v.y); o.z = f2b(v.z); o.w = f2b(v.w);
  *reinterpret_cast<us4*>(dst + i) = o;
}

// d = bne @ Wen + ben   (1 block, 256 threads; coalesced over j)
__global__ void dvec_kernel(const float* __restrict__ bne, const float* __restrict__ Wen,
                            const float* __restrict__ ben, float* __restrict__ d) {
  const int j = threadIdx.x;
  float s = ben[j];
  for (int k = 0; k < LATD; ++k) s += bne[k] * Wen[k * LATD + j];
  d[j] = s;
}

// ---------------- segment mean (one wave per segment), bf16 src ----------------

__global__ __launch_bounds__(256) void agg_kernel(const u16* __restrict__ src,
                                                  const int* __restrict__ off,
                                                  const int* __restrict__ lst,
                                                  const float* __restrict__ recip,
                                                  u16* __restrict__ dst, int nseg) {
  const int lane = threadIdx.x & 63;
  const int seg = (blockIdx.x << 2) + (threadIdx.x >> 6);
  if (seg >= nseg) return;
  const int s = off[seg], e = off[seg + 1];
  float a0 = 0.f, a1 = 0.f, a2 = 0.f, a3 = 0.f;
  for (int p = s; p < e; ++p) {
    int r = lst[p];
    us4 v = *(reinterpret_cast<const us4*>(src + (size_t)r * LATD) + lane);
    a0 += b2f(v.x); a1 += b2f(v.y); a2 += b2f(v.z); a3 += b2f(v.w);
  }
  const float rc = recip[seg];
  us4 o;
  o.x = f2b(a0 * rc); o.y = f2b(a1 * rc); o.z = f2b(a2 * rc); o.w = f2b(a3 * rc);
  *(reinterpret_cast<us4*>(dst + (size_t)seg * LATD) + lane) = o;
}

// ---------------- MFMA GEMM with LDS-staged coalesced epilogue ----------------
// C = A[MxK](bf16) * BT[NxK]^T(bf16) (+ bias), 128x128 tile, 4 waves.
// RK modes use the u-trick: stage1 stores u = C(z); stages 2-4 compute
// k_i = tanh(u + c * L(k_{i-1})) without touching z; stage 4 updates z.

enum { EPI_RELU_BF16, EPI_BF16, EPI_F32, EPI_F32_ZT, EPI_U1, EPI_U23, EPI_U4 };

template <int MODE>
__global__ __launch_bounds__(256) void gemm_kernel(
    const u16* __restrict__ A, const u16* __restrict__ BT, const float* __restrict__ bias,
    int M, int N, int K,
    u16* __restrict__ outb, float* __restrict__ outf,
    u16* __restrict__ ubuf, u16* __restrict__ accbuf, float* __restrict__ zbuf, float czt) {
  __shared__ char smem[4 * 16 * 66 * 4];  // 16896B; GEMM phase uses first 16KB
  u16* lA = (u16*)smem;
  u16* lB = (u16*)(smem + 8192);
  const int t = threadIdx.x;
  const int m0 = blockIdx.x * 128, n0 = blockIdx.y * 128;
  const int srow = t >> 2;
  const int gslot = (t & 3) ^ ((srow >> 1) & 3);

  int ar0 = m0 + srow;      if (ar0 > M - 1) ar0 = M - 1;
  int ar1 = m0 + srow + 64; if (ar1 > M - 1) ar1 = M - 1;
  const u16* gA0 = A + (size_t)ar0 * K + gslot * 8;
  const u16* gA1 = A + (size_t)ar1 * K + gslot * 8;
  const u16* gB0 = BT + (size_t)(n0 + srow) * K + gslot * 8;
  const u16* gB1 = BT + (size_t)(n0 + srow + 64) * K + gslot * 8;
  char* lAd0 = (char*)lA + t * 16; char* lAd1 = lAd0 + 4096;
  char* lBd0 = (char*)lB + t * 16; char* lBd1 = lBd0 + 4096;

  const int lane = t & 63, wid = t >> 6;
  const int wm = wid >> 1, wn = wid & 1;
  const int lrow = lane & 15, kg = lane >> 4;

  f32x4 acc[4][4] = {};
  const char* lAb = (const char*)lA;
  const char* lBb = (const char*)lB;

  for (int kk = 0; kk < K; kk += 32) {
    async16(gA0 + kk, lAd0);
    async16(gA1 + kk, lAd1);
    async16(gB0 + kk, lBd0);
    async16(gB1 + kk, lBd1);
    __syncthreads();
    bf16x8 af[4], bg[4];
#pragma unroll
    for (int i = 0; i < 4; ++i) {
      int rA = wm * 64 + i * 16 + lrow;
      af[i] = *(const bf16x8*)(lAb + rA * 64 + (((kg ^ (rA >> 1)) & 3) << 4));
      int rB = wn * 64 + i * 16 + lrow;
      bg[i] = *(const bf16x8*)(lBb + rB * 64 + (((kg ^ (rB >> 1)) & 3) << 4));
    }
#pragma unroll
    for (int i = 0; i < 4; ++i)
#pragma unroll
      for (int j = 0; j < 4; ++j)
        acc[i][j] = __builtin_amdgcn_mfma_f32_16x16x32_bf16(af[i], bg[j], acc[i][j], 0, 0, 0);
    __syncthreads();
  }

  // ---- staged epilogue (wave-private LDS region; no barriers needed) ----
  constexpr bool USE_BIAS = (MODE != EPI_U23 && MODE != EPI_U4);
  float* stage = (float*)smem + wid * (16 * 66);
  const int rr = lane >> 3;
  const int c0 = (lane & 7) * 8;
  const float dt6 = 0.125f / 6.0f;

#pragma unroll
  for (int ti = 0; ti < 4; ++ti) {
#pragma unroll
    for (int tj = 0; tj < 4; ++tj) {
      const float bv = USE_BIAS ? bias[n0 + wn * 64 + tj * 16 + lrow] : 0.0f;
#pragma unroll
      for (int j = 0; j < 4; ++j)
        stage[(kg * 4 + j) * 66 + tj * 16 + lrow] = acc[ti][tj][j] + bv;
    }
#pragma unroll
    for (int pass = 0; pass < 2; ++pass) {
      const int r = pass * 8 + rr;
      const int gr = m0 + wm * 64 + ti * 16 + r;
      if (gr >= M) continue;
      const int gc = n0 + wn * 64 + c0;
      const size_t idx = (size_t)gr * N + gc;
      float v[8];
      *(float4*)v = *(const float4*)&stage[r * 66 + c0];
      *(float4*)(v + 4) = *(const float4*)&stage[r * 66 + c0 + 4];

      if constexpr (MODE == EPI_RELU_BF16 || MODE == EPI_BF16) {
        us8 o;
#pragma unroll
        for (int e2 = 0; e2 < 8; ++e2)
          o[e2] = f2b(MODE == EPI_RELU_BF16 ? fmaxf(v[e2], 0.0f) : v[e2]);
        *(us8*)(outb + idx) = o;
      } else if constexpr (MODE == EPI_F32 || MODE == EPI_F32_ZT) {
        *(float4*)(outf + idx) = *(float4*)v;
        *(float4*)(outf + idx + 4) = *(float4*)(v + 4);
        if constexpr (MODE == EPI_F32_ZT) {
          us8 o;
#pragma unroll
          for (int e2 = 0; e2 < 8; ++e2) o[e2] = f2b(v[e2]);
          *(us8*)(outb + idx) = o;
        }
      } else if constexpr (MODE == EPI_U1) {
        // u = C(z) (bias d already added); k1 = tanh(u); acc = k1
        us8 uo, ko;
#pragma unroll
        for (int e2 = 0; e2 < 8; ++e2) {
          uo[e2] = f2b(v[e2]);
          ko[e2] = f2b(fast_tanh(v[e2]));
        }
        *(us8*)(ubuf + idx) = uo;
        *(us8*)(outb + idx) = ko;     // kbuf (stage-2 input)
        *(us8*)(accbuf + idx) = ko;   // acc = k1
      } else if constexpr (MODE == EPI_U23) {
        // k_i = tanh(u + c * L(k_{i-1})); acc += 2*k_i
        us8 uv = *(const us8*)(ubuf + idx);
        us8 av = *(const us8*)(accbuf + idx);
        us8 ko, ao;
#pragma unroll
        for (int e2 = 0; e2 < 8; ++e2) {
          float kv = fast_tanh(b2f(uv[e2]) + czt * v[e2]);
          ko[e2] = f2b(kv);
          ao[e2] = f2b(b2f(av[e2]) + 2.0f * kv);
        }
        *(us8*)(outb + idx) = ko;
        *(us8*)(accbuf + idx) = ao;
      } else {  // EPI_U4
        us8 uv = *(const us8*)(ubuf + idx);
        us8 av = *(const us8*)(accbuf + idx);
        float4 z0 = *(const float4*)(zbuf + idx);
        float4 z1 = *(const float4*)(zbuf + idx + 4);
        float zn[8];
        us8 zo;
#pragma unroll
        for (int e2 = 0; e2 < 8; ++e2) {
          float kv = fast_tanh(b2f(uv[e2]) + czt * v[e2]);
          float zv = (e2 < 4) ? ((const float*)&z0)[e2] : ((const float*)&z1)[e2 - 4];
          zn[e2] = zv + dt6 * (b2f(av[e2]) + kv);
          zo[e2] = f2b(zn[e2]);
        }
        *(float4*)(zbuf + idx) = *(float4*)zn;
        *(float4*)(zbuf + idx + 4) = *(float4*)(zn + 4);
        *(us8*)(outb + idx) = zo;     // zt for next step / decode
      }
    }
  }
}

// ---------------- launch ----------------

extern "C" void kernel_launch(void* const* d_in, const int* in_sizes, int n_in,
                              void* d_out, int out_size, void* d_ws, size_t ws_size,
                              hipStream_t stream) {
  const float* X = (const float*)d_in[0];
  const float* encW0 = (const float*)d_in[1];
  const float* encb0 = (const float*)d_in[2];
  const float* encW1 = (const float*)d_in[3];
  const float* encb1 = (const float*)d_in[4];
  const float* Wne = (const float*)d_in[5];
  const float* bne = (const float*)d_in[6];
  const float* Wen = (const float*)d_in[7];
  const float* ben = (const float*)d_in[8];
  const float* decW0 = (const float*)d_in[9];
  const float* decb0 = (const float*)d_in[10];
  const float* decW1 = (const float*)d_in[11];
  const float* decb1 = (const float*)d_in[12];
  const int* node_idx = (const int*)d_in[13];
  const int* edge_idx = (const int*)d_in[14];
  float* out = (float*)d_out;

  char* p = (char*)d_ws;
  auto alloc = [&](size_t bytes) {
    char* r = p;
    p += (bytes + 255) & ~(size_t)255;
    return r;
  };
  float* z      = (float*)alloc((size_t)NN * LATD * 4);
  u16* ubuf     = (u16*)alloc((size_t)NN * LATD * 2);
  u16* accb     = (u16*)alloc((size_t)NN * LATD * 2);
  u16* xin      = (u16*)alloc((size_t)NN * LATD * 2);   // zt / kbuf (liveness-disjoint)
  u16* mh       = (u16*)alloc((size_t)NN * LATD * 2);
  u16* eagg     = (u16*)alloc((size_t)NE * LATD * 2);
  u16* encW0T   = (u16*)alloc((size_t)OBSD * LATD * 2);
  u16* encW1T   = (u16*)alloc((size_t)LATD * LATD * 2);
  u16* WneB     = (u16*)alloc((size_t)LATD * LATD * 2);  // bf16(Wne), row-major
  u16* WenT     = (u16*)alloc((size_t)LATD * LATD * 2);
  u16* WcT      = (u16*)alloc((size_t)LATD * LATD * 2);  // (Wne@Wen)^T
  u16* decW0T   = (u16*)alloc((size_t)LATD * LATD * 2);
  u16* decW1T   = (u16*)alloc((size_t)LATD * OBSD * 2);
  float* dvec   = (float*)alloc(LATD * 4);
  float* zeros  = (float*)alloc(LATD * 4);
  int* cnt      = (int*)alloc((size_t)(NE + NN) * 4);
  int* cnt_e = cnt; int* cnt_n = cnt + NE;
  int* off_e    = (int*)alloc((size_t)(NE + 1) * 4);
  int* off_n    = (int*)alloc((size_t)(NN + 1) * 4);
  int* cur_e    = (int*)alloc((size_t)NE * 4);
  int* cur_n    = (int*)alloc((size_t)NN * 4);
  int* lst_e    = (int*)alloc((size_t)NNZC * 4);
  int* lst_n    = (int*)alloc((size_t)NNZC * 4);
  float* recip_e = (float*)alloc((size_t)NE * 4);
  float* recip_n = (float*)alloc((size_t)NN * 4);
  int* bsum_e   = (int*)alloc(16 * 4);
  int* bsum_n   = (int*)alloc(64 * 4);

  size_t needed = (size_t)(p - (char*)d_ws);
  if (needed > ws_size) {
    hipMemsetAsync(d_out, 0x7F, (size_t)out_size * 4, stream);
    return;
  }

  const int nbe = (NE + 1023) / 1024, nbn = (NN + 1023) / 1024;

  // CSR build
  hipMemsetAsync(cnt, 0, (size_t)(NE + NN) * 4, stream);
  count_kernel<<<(NNZC + 255) / 256, 256, 0, stream>>>(node_idx, edge_idx, cnt_n, cnt_e, NNZC);
  scan1_kernel<<<nbe, 1024, 0, stream>>>(cnt_e, off_e, bsum_e, NE);
  scan1_kernel<<<nbn, 1024, 0, stream>>>(cnt_n, off_n, bsum_n, NN);
  scan2_kernel<<<1, 64, 0, stream>>>(bsum_e, nbe);
  scan2_kernel<<<1, 64, 0, stream>>>(bsum_n, nbn);
  scan3_kernel<<<(NE + 255) / 256, 256, 0, stream>>>(cnt_e, off_e, cur_e, recip_e, bsum_e, NE);
  scan3_kernel<<<(NN + 255) / 256, 256, 0, stream>>>(cnt_n, off_n, cur_n, recip_n, bsum_n, NN);
  fill_kernel<<<(NNZC + 255) / 256, 256, 0, stream>>>(node_idx, edge_idx, cur_n, cur_e, lst_n, lst_e, NNZC);

  // weight prep
  transpose_kernel<<<(OBSD * LATD + 255) / 256, 256, 0, stream>>>(encW0, encW0T, OBSD, LATD);
  transpose_kernel<<<(LATD * LATD + 255) / 256, 256, 0, stream>>>(encW1, encW1T, LATD, LATD);
  transpose_kernel<<<(LATD * LATD + 255) / 256, 256, 0, stream>>>(Wen, WenT, LATD, LATD);
  transpose_kernel<<<(LATD * LATD + 255) / 256, 256, 0, stream>>>(decW0, decW0T, LATD, LATD);
  transpose_kernel<<<(LATD * OBSD + 255) / 256, 256, 0, stream>>>(decW1, decW1T, LATD, OBSD);
  to_bf16_kernel<<<(LATD * LATD / 4 + 255) / 256, 256, 0, stream>>>(Wne, WneB, LATD * LATD);
  hipMemsetAsync(zeros, 0, LATD * 4, stream);
  dvec_kernel<<<1, LATD, 0, stream>>>(bne, Wen, ben, dvec);
  // WcT[n,k] = (Wne@Wen)[k,n] via C = WenT @ WneB^T
  gemm_kernel<EPI_BF16><<<dim3(2, 2), 256, 0, stream>>>(WenT, WneB, zeros, LATD, LATD, LATD,
                                                        WcT, nullptr, nullptr, nullptr, nullptr, 0.f);

  const dim3 blk(256);
  const dim3 g50((NN + 127) / 128, LATD / 128);   // (391, 2)
  const dim3 gdec((NN + 127) / 128, OBSD / 128);  // (391, 1)

  // encode: h1 = relu(X@W0+b0) ; z = h1@W1+b1 (f32 + bf16 shadow in xin)
  to_bf16_kernel<<<(NN * OBSD / 4 + 255) / 256, 256, 0, stream>>>(X, xin, NN * OBSD);
  gemm_kernel<EPI_RELU_BF16><<<g50, blk, 0, stream>>>(xin, encW0T, encb0, NN, LATD, OBSD,
                                                      mh, nullptr, nullptr, nullptr, nullptr, 0.f);
  gemm_kernel<EPI_F32_ZT><<<g50, blk, 0, stream>>>(mh, encW1T, encb1, NN, LATD, LATD,
                                                   xin, z, nullptr, nullptr, nullptr, 0.f);

  // RK4 steps: 3 kernels per substep (u-trick; xin holds zt for stage1, k_{i-1} after)
  for (int s = 0; s < NSTEPS; ++s) {
    for (int k = 0; k < 4; ++k) {
      agg_kernel<<<(NE + 3) / 4, blk, 0, stream>>>(xin, off_e, lst_e, recip_e, eagg, NE);
      agg_kernel<<<(NN + 3) / 4, blk, 0, stream>>>(eagg, off_n, lst_n, recip_n, mh, NN);
      if (k == 0)
        gemm_kernel<EPI_U1><<<g50, blk, 0, stream>>>(mh, WcT, dvec, NN, LATD, LATD,
                                                     xin, nullptr, ubuf, accb, nullptr, 0.f);
      else if (k == 3)
        gemm_kernel<EPI_U4><<<g50, blk, 0, stream>>>(mh, WcT, nullptr, NN, LATD, LATD,
                                                     xin, nullptr, ubuf, accb, z, 0.125f);
      else
        gemm_kernel<EPI_U23><<<g50, blk, 0, stream>>>(mh, WcT, nullptr, NN, LATD, LATD,
                                                      xin, nullptr, ubuf, accb, nullptr, 0.0625f);
    }
  }

  // decode (xin holds bf16(z) from U4)
  gemm_kernel<EPI_RELU_BF16><<<g50, blk, 0, stream>>>(xin, decW0T, decb0, NN, LATD, LATD,
                                                      mh, nullptr, nullptr, nullptr, nullptr, 0.f);
  gemm_kernel<EPI_F32><<<gdec, blk, 0, stream>>>(mh, decW1T, decb1, NN, OBSD, LATD,
                                                 nullptr, out, nullptr, nullptr, nullptr, 0.f);
}

// Round 5
// 2199.109 us; speedup vs baseline: 2.6621x; 1.4970x over previous
//
#include <hip/hip_runtime.h>

#define NN 50000
#define NE 10000
#define NNZC 200000
#define OBSD 128
#define LATD 256
#define NSTEPS 8

typedef unsigned short u16;
typedef __attribute__((ext_vector_type(8))) short bf16x8;
typedef __attribute__((ext_vector_type(4))) float f32x4;
typedef __attribute__((ext_vector_type(4))) u16 us4;
typedef __attribute__((ext_vector_type(8))) u16 us8;

__device__ __forceinline__ u16 f2b(float f) {
  unsigned int u = __builtin_bit_cast(unsigned int, f);
  u = (u + 0x7FFFu + ((u >> 16) & 1u)) >> 16;
  return (u16)u;
}
__device__ __forceinline__ float b2f(u16 h) {
  unsigned int u = ((unsigned int)h) << 16;
  return __builtin_bit_cast(float, u);
}
__device__ __forceinline__ float fast_tanh(float x) {
  float e = __expf(2.0f * x);
  return 1.0f - 2.0f / (e + 1.0f);
}

typedef __attribute__((address_space(1))) const unsigned int GU32;
typedef __attribute__((address_space(3))) unsigned int LU32;
__device__ __forceinline__ void async16(const void* g, void* l) {
  __builtin_amdgcn_global_load_lds((GU32*)g, (LU32*)l, 16, 0, 0);
}

// ---------------- CSR build ----------------

__global__ void count_kernel(const int* __restrict__ ni, const int* __restrict__ ei,
                             int* __restrict__ cnt_n, int* __restrict__ cnt_e, int nnz) {
  int i = blockIdx.x * blockDim.x + threadIdx.x;
  if (i < nnz) {
    atomicAdd(&cnt_n[ni[i]], 1);
    atomicAdd(&cnt_e[ei[i]], 1);
  }
}

__global__ __launch_bounds__(1024) void scan1_kernel(const int* __restrict__ cnt,
                                                     int* __restrict__ off,
                                                     int* __restrict__ bsum, int n) {
  __shared__ int ws[16];
  const int tid = threadIdx.x;
  const int lane = tid & 63, w = tid >> 6;
  const int i = blockIdx.x * 1024 + tid;
  int v = (i < n) ? cnt[i] : 0;
  int s = v;
#pragma unroll
  for (int d = 1; d < 64; d <<= 1) {
    int t2 = __shfl_up(s, d);
    if (lane >= d) s += t2;
  }
  if (lane == 63) ws[w] = s;
  __syncthreads();
  if (w == 0) {
    int x = (lane < 16) ? ws[lane] : 0;
#pragma unroll
    for (int d = 1; d < 16; d <<= 1) {
      int t2 = __shfl_up(x, d);
      if (lane >= d) x += t2;
    }
    if (lane < 16) ws[lane] = x;
  }
  __syncthreads();
  const int base = w ? ws[w - 1] : 0;
  if (i < n) off[i] = base + s - v;
  if (tid == 0) bsum[blockIdx.x] = ws[15];
}

__global__ void scan2_kernel(int* __restrict__ bsum, int nb) {
  const int lane = threadIdx.x;
  int v = (lane < nb) ? bsum[lane] : 0;
  int s = v;
#pragma unroll
  for (int d = 1; d < 64; d <<= 1) {
    int t2 = __shfl_up(s, d);
    if (lane >= d) s += t2;
  }
  if (lane < nb) bsum[lane] = s - v;
  if (lane == 63) bsum[nb] = s;
}

__global__ void scan3_kernel(const int* __restrict__ cnt, int* __restrict__ off,
                             int* __restrict__ cur, float* __restrict__ recip,
                             const int* __restrict__ bsum, int n) {
  const int i = blockIdx.x * blockDim.x + threadIdx.x;
  if (i < n) {
    const int o = off[i] + bsum[i >> 10];
    off[i] = o;
    cur[i] = o;
    recip[i] = 1.0f / fmaxf((float)cnt[i], 1.0f);
  }
  if (i == 0) off[n] = bsum[(n + 1023) >> 10];
}

__global__ void fill_kernel(const int* __restrict__ ni, const int* __restrict__ ei,
                            int* __restrict__ cur_n, int* __restrict__ cur_e,
                            int* __restrict__ lst_n, int* __restrict__ lst_e, int nnz) {
  int i = blockIdx.x * blockDim.x + threadIdx.x;
  if (i < nnz) {
    int n = ni[i], e = ei[i];
    lst_e[atomicAdd(&cur_e[e], 1)] = n;
    lst_n[atomicAdd(&cur_n[n], 1)] = e;
  }
}

// ---------------- small prep ----------------

__global__ void transpose_kernel(const float* __restrict__ W, u16* __restrict__ WT, int K, int N) {
  int i = blockIdx.x * blockDim.x + threadIdx.x;
  if (i >= K * N) return;
  int k = i / N, n = i - k * N;
  WT[n * K + k] = f2b(W[i]);
}

__global__ void to_bf16_kernel(const float* __restrict__ src, u16* __restrict__ dst, int n) {
  int i = (blockIdx.x * blockDim.x + threadIdx.x) * 4;
  if (i >= n) return;
  float4 v = *reinterpret_cast<const float4*>(src + i);
  us4 o;
  o.x = f2b(v.x); o.y = f2b(v.y); o.z = f2b(v.z); o.w = f2b(v.w);
  *reinterpret_cast<us4*>(dst + i) = o;
}

// d = bne @ Wen + ben
__global__ void dvec_kernel(const float* __restrict__ bne, const float* __restrict__ Wen,
                            const float* __restrict__ ben, float* __restrict__ d) {
  const int j = threadIdx.x;
  float s = ben[j];
  for (int k = 0; k < LATD; ++k) s += bne[k] * Wen[k * LATD + j];
  d[j] = s;
}

// ---------------- segment mean: 2 segments per wave, us8 lanes ----------------

__global__ __launch_bounds__(256) void agg_kernel(const u16* __restrict__ src,
                                                  const int* __restrict__ off,
                                                  const int* __restrict__ lst,
                                                  const float* __restrict__ recip,
                                                  u16* __restrict__ dst, int nseg) {
  const int t = threadIdx.x;
  const int cl = t & 31;
  const int seg = blockIdx.x * 8 + (t >> 5);
  if (seg >= nseg) return;
  const int s = off[seg], e = off[seg + 1];
  float a[8] = {};
  for (int p = s; p < e; ++p) {
    const int r = lst[p];
    us8 v = *(reinterpret_cast<const us8*>(src + (size_t)r * LATD) + cl);
#pragma unroll
    for (int j = 0; j < 8; ++j) a[j] += b2f(v[j]);
  }
  const float rc = recip[seg];
  us8 o;
#pragma unroll
  for (int j = 0; j < 8; ++j) o[j] = f2b(a[j] * rc);
  *(reinterpret_cast<us8*>(dst + (size_t)seg * LATD) + cl) = o;
}

// ---------------- fused node-gather + RK epilogue (streaming, no LDS) ----------------
// STAGE 0: u = mean + d; k1 = tanh(u); write u, k1
// STAGE 1/2: k_i = tanh(u + c*mean); write k2/k3
// STAGE 3: k4 = tanh(u + c*mean); z += dt/6*(k1+2k2+2k3+k4); write zhi, zlo

template <int STAGE>
__global__ __launch_bounds__(256) void aggn_epi_kernel(
    const u16* __restrict__ G, const int* __restrict__ off, const int* __restrict__ lst,
    const float* __restrict__ recip, const float* __restrict__ dvec,
    u16* __restrict__ ub, u16* __restrict__ k1b, u16* __restrict__ k2b,
    u16* __restrict__ k3b, u16* __restrict__ zhi, u16* __restrict__ zlo, float c) {
  const int t = threadIdx.x;
  const int cl = t & 31;
  const int node = blockIdx.x * 8 + (t >> 5);
  if (node >= NN) return;
  const int s = off[node], e = off[node + 1];
  float v[8] = {};
  for (int p = s; p < e; ++p) {
    const int er = lst[p];
    us8 g = *(reinterpret_cast<const us8*>(G + (size_t)er * LATD) + cl);
#pragma unroll
    for (int j = 0; j < 8; ++j) v[j] += b2f(g[j]);
  }
  const float rc = recip[node];
  const size_t base = (size_t)node * LATD + cl * 8;
  const float dt6 = 0.125f / 6.0f;

  if constexpr (STAGE == 0) {
    us8 uo, ko;
#pragma unroll
    for (int j = 0; j < 8; ++j) {
      const float u = v[j] * rc + dvec[cl * 8 + j];
      uo[j] = f2b(u);
      ko[j] = f2b(fast_tanh(u));
    }
    *(us8*)(ub + base) = uo;
    *(us8*)(k1b + base) = ko;
  } else if constexpr (STAGE == 1 || STAGE == 2) {
    us8 uv = *(const us8*)(ub + base);
    us8 ko;
#pragma unroll
    for (int j = 0; j < 8; ++j)
      ko[j] = f2b(fast_tanh(b2f(uv[j]) + c * (v[j] * rc)));
    *(us8*)((STAGE == 1 ? k2b : k3b) + base) = ko;
  } else {
    us8 uv = *(const us8*)(ub + base);
    us8 a1 = *(const us8*)(k1b + base);
    us8 a2 = *(const us8*)(k2b + base);
    us8 a3 = *(const us8*)(k3b + base);
    us8 zh = *(const us8*)(zhi + base);
    us8 zl = *(const us8*)(zlo + base);
    us8 ho, lo;
#pragma unroll
    for (int j = 0; j < 8; ++j) {
      const float k4 = fast_tanh(b2f(uv[j]) + c * (v[j] * rc));
      const float zn = (b2f(zh[j]) + b2f(zl[j]))
                     + dt6 * (b2f(a1[j]) + 2.0f * b2f(a2[j]) + 2.0f * b2f(a3[j]) + k4);
      const u16 h = f2b(zn);
      ho[j] = h;
      lo[j] = f2b(zn - b2f(h));
    }
    *(us8*)(zhi + base) = ho;
    *(us8*)(zlo + base) = lo;
  }
}

// ---------------- MFMA GEMM with LDS-staged coalesced epilogue ----------------

enum { EPI_RELU_BF16, EPI_BF16, EPI_F32, EPI_SPLIT };

template <int MODE>
__global__ __launch_bounds__(256) void gemm_kernel(
    const u16* __restrict__ A, const u16* __restrict__ BT, const float* __restrict__ bias,
    int M, int N, int K,
    u16* __restrict__ outb, u16* __restrict__ outb2, float* __restrict__ outf) {
  __shared__ char smem[4 * 16 * 66 * 4];  // 16896B; GEMM phase uses first 16KB
  u16* lA = (u16*)smem;
  u16* lB = (u16*)(smem + 8192);
  const int t = threadIdx.x;
  const int m0 = blockIdx.x * 128, n0 = blockIdx.y * 128;
  const int srow = t >> 2;
  const int gslot = (t & 3) ^ ((srow >> 1) & 3);

  int ar0 = m0 + srow;      if (ar0 > M - 1) ar0 = M - 1;
  int ar1 = m0 + srow + 64; if (ar1 > M - 1) ar1 = M - 1;
  const u16* gA0 = A + (size_t)ar0 * K + gslot * 8;
  const u16* gA1 = A + (size_t)ar1 * K + gslot * 8;
  const u16* gB0 = BT + (size_t)(n0 + srow) * K + gslot * 8;
  const u16* gB1 = BT + (size_t)(n0 + srow + 64) * K + gslot * 8;
  char* lAd0 = (char*)lA + t * 16; char* lAd1 = lAd0 + 4096;
  char* lBd0 = (char*)lB + t * 16; char* lBd1 = lBd0 + 4096;

  const int lane = t & 63, wid = t >> 6;
  const int wm = wid >> 1, wn = wid & 1;
  const int lrow = lane & 15, kg = lane >> 4;

  f32x4 acc[4][4] = {};
  const char* lAb = (const char*)lA;
  const char* lBb = (const char*)lB;

  for (int kk = 0; kk < K; kk += 32) {
    async16(gA0 + kk, lAd0);
    async16(gA1 + kk, lAd1);
    async16(gB0 + kk, lBd0);
    async16(gB1 + kk, lBd1);
    __syncthreads();
    bf16x8 af[4], bg[4];
#pragma unroll
    for (int i = 0; i < 4; ++i) {
      int rA = wm * 64 + i * 16 + lrow;
      af[i] = *(const bf16x8*)(lAb + rA * 64 + (((kg ^ (rA >> 1)) & 3) << 4));
      int rB = wn * 64 + i * 16 + lrow;
      bg[i] = *(const bf16x8*)(lBb + rB * 64 + (((kg ^ (rB >> 1)) & 3) << 4));
    }
#pragma unroll
    for (int i = 0; i < 4; ++i)
#pragma unroll
      for (int j = 0; j < 4; ++j)
        acc[i][j] = __builtin_amdgcn_mfma_f32_16x16x32_bf16(af[i], bg[j], acc[i][j], 0, 0, 0);
    __syncthreads();
  }

  // staged epilogue (wave-private LDS region)
  float* stage = (float*)smem + wid * (16 * 66);
  const int rr = lane >> 3;
  const int c0 = (lane & 7) * 8;

#pragma unroll
  for (int ti = 0; ti < 4; ++ti) {
#pragma unroll
    for (int tj = 0; tj < 4; ++tj) {
      const float bv = bias[n0 + wn * 64 + tj * 16 + lrow];
#pragma unroll
      for (int j = 0; j < 4; ++j)
        stage[(kg * 4 + j) * 66 + tj * 16 + lrow] = acc[ti][tj][j] + bv;
    }
#pragma unroll
    for (int pass = 0; pass < 2; ++pass) {
      const int r = pass * 8 + rr;
      const int gr = m0 + wm * 64 + ti * 16 + r;
      if (gr >= M) continue;
      const int gc = n0 + wn * 64 + c0;
      const size_t idx = (size_t)gr * N + gc;
      float v[8];
      *(float4*)v = *(const float4*)&stage[r * 66 + c0];
      *(float4*)(v + 4) = *(const float4*)&stage[r * 66 + c0 + 4];

      if constexpr (MODE == EPI_RELU_BF16 || MODE == EPI_BF16) {
        us8 o;
#pragma unroll
        for (int e2 = 0; e2 < 8; ++e2)
          o[e2] = f2b(MODE == EPI_RELU_BF16 ? fmaxf(v[e2], 0.0f) : v[e2]);
        *(us8*)(outb + idx) = o;
      } else if constexpr (MODE == EPI_F32) {
        *(float4*)(outf + idx) = *(float4*)v;
        *(float4*)(outf + idx + 4) = *(float4*)(v + 4);
      } else {  // EPI_SPLIT: z -> bf16 hi + lo planes
        us8 ho, lo;
#pragma unroll
        for (int e2 = 0; e2 < 8; ++e2) {
          const u16 h = f2b(v[e2]);
          ho[e2] = h;
          lo[e2] = f2b(v[e2] - b2f(h));
        }
        *(us8*)(outb + idx) = ho;
        *(us8*)(outb2 + idx) = lo;
      }
    }
  }
}

// ---------------- launch ----------------

extern "C" void kernel_launch(void* const* d_in, const int* in_sizes, int n_in,
                              void* d_out, int out_size, void* d_ws, size_t ws_size,
                              hipStream_t stream) {
  const float* X = (const float*)d_in[0];
  const float* encW0 = (const float*)d_in[1];
  const float* encb0 = (const float*)d_in[2];
  const float* encW1 = (const float*)d_in[3];
  const float* encb1 = (const float*)d_in[4];
  const float* Wne = (const float*)d_in[5];
  const float* bne = (const float*)d_in[6];
  const float* Wen = (const float*)d_in[7];
  const float* ben = (const float*)d_in[8];
  const float* decW0 = (const float*)d_in[9];
  const float* decb0 = (const float*)d_in[10];
  const float* decW1 = (const float*)d_in[11];
  const float* decb1 = (const float*)d_in[12];
  const int* node_idx = (const int*)d_in[13];
  const int* edge_idx = (const int*)d_in[14];
  float* out = (float*)d_out;

  char* p = (char*)d_ws;
  auto alloc = [&](size_t bytes) {
    char* r = p;
    p += (bytes + 255) & ~(size_t)255;
    return r;
  };
  u16* zhi      = (u16*)alloc((size_t)NN * LATD * 2);
  u16* zlo      = (u16*)alloc((size_t)NN * LATD * 2);
  u16* ub       = (u16*)alloc((size_t)NN * LATD * 2);
  u16* k1b      = (u16*)alloc((size_t)NN * LATD * 2);   // also mh in encode/decode
  u16* k2b      = (u16*)alloc((size_t)NN * LATD * 2);   // also bf16(X) in encode
  u16* k3b      = (u16*)alloc((size_t)NN * LATD * 2);
  u16* eagg     = (u16*)alloc((size_t)NE * LATD * 2);
  u16* G        = (u16*)alloc((size_t)NE * LATD * 2);
  u16* encW0T   = (u16*)alloc((size_t)OBSD * LATD * 2);
  u16* encW1T   = (u16*)alloc((size_t)LATD * LATD * 2);
  u16* WneB     = (u16*)alloc((size_t)LATD * LATD * 2);
  u16* WenT     = (u16*)alloc((size_t)LATD * LATD * 2);
  u16* WcT      = (u16*)alloc((size_t)LATD * LATD * 2);
  u16* decW0T   = (u16*)alloc((size_t)LATD * LATD * 2);
  u16* decW1T   = (u16*)alloc((size_t)LATD * OBSD * 2);
  float* dvec   = (float*)alloc(LATD * 4);
  float* zeros  = (float*)alloc(LATD * 4);
  int* cnt      = (int*)alloc((size_t)(NE + NN) * 4);
  int* cnt_e = cnt; int* cnt_n = cnt + NE;
  int* off_e    = (int*)alloc((size_t)(NE + 1) * 4);
  int* off_n    = (int*)alloc((size_t)(NN + 1) * 4);
  int* cur_e    = (int*)alloc((size_t)NE * 4);
  int* cur_n    = (int*)alloc((size_t)NN * 4);
  int* lst_e    = (int*)alloc((size_t)NNZC * 4);
  int* lst_n    = (int*)alloc((size_t)NNZC * 4);
  float* recip_e = (float*)alloc((size_t)NE * 4);
  float* recip_n = (float*)alloc((size_t)NN * 4);
  int* bsum_e   = (int*)alloc(16 * 4);
  int* bsum_n   = (int*)alloc(64 * 4);

  size_t needed = (size_t)(p - (char*)d_ws);
  if (needed > ws_size) {
    hipMemsetAsync(d_out, 0x7F, (size_t)out_size * 4, stream);
    return;
  }

  const int nbe = (NE + 1023) / 1024, nbn = (NN + 1023) / 1024;

  // CSR build
  hipMemsetAsync(cnt, 0, (size_t)(NE + NN) * 4, stream);
  count_kernel<<<(NNZC + 255) / 256, 256, 0, stream>>>(node_idx, edge_idx, cnt_n, cnt_e, NNZC);
  scan1_kernel<<<nbe, 1024, 0, stream>>>(cnt_e, off_e, bsum_e, NE);
  scan1_kernel<<<nbn, 1024, 0, stream>>>(cnt_n, off_n, bsum_n, NN);
  scan2_kernel<<<1, 64, 0, stream>>>(bsum_e, nbe);
  scan2_kernel<<<1, 64, 0, stream>>>(bsum_n, nbn);
  scan3_kernel<<<(NE + 255) / 256, 256, 0, stream>>>(cnt_e, off_e, cur_e, recip_e, bsum_e, NE);
  scan3_kernel<<<(NN + 255) / 256, 256, 0, stream>>>(cnt_n, off_n, cur_n, recip_n, bsum_n, NN);
  fill_kernel<<<(NNZC + 255) / 256, 256, 0, stream>>>(node_idx, edge_idx, cur_n, cur_e, lst_n, lst_e, NNZC);

  // weight prep
  transpose_kernel<<<(OBSD * LATD + 255) / 256, 256, 0, stream>>>(encW0, encW0T, OBSD, LATD);
  transpose_kernel<<<(LATD * LATD + 255) / 256, 256, 0, stream>>>(encW1, encW1T, LATD, LATD);
  transpose_kernel<<<(LATD * LATD + 255) / 256, 256, 0, stream>>>(Wen, WenT, LATD, LATD);
  transpose_kernel<<<(LATD * LATD + 255) / 256, 256, 0, stream>>>(decW0, decW0T, LATD, LATD);
  transpose_kernel<<<(LATD * OBSD + 255) / 256, 256, 0, stream>>>(decW1, decW1T, LATD, OBSD);
  to_bf16_kernel<<<(LATD * LATD / 4 + 255) / 256, 256, 0, stream>>>(Wne, WneB, LATD * LATD);
  hipMemsetAsync(zeros, 0, LATD * 4, stream);
  dvec_kernel<<<1, LATD, 0, stream>>>(bne, Wen, ben, dvec);
  gemm_kernel<EPI_BF16><<<dim3(2, 2), 256, 0, stream>>>(WenT, WneB, zeros, LATD, LATD, LATD,
                                                        WcT, nullptr, nullptr);

  const dim3 blk(256);
  const dim3 g50((NN + 127) / 128, LATD / 128);   // (391, 2)
  const dim3 g10((NE + 127) / 128, LATD / 128);   // (79, 2)
  const dim3 gdec((NN + 127) / 128, OBSD / 128);  // (391, 1)
  const dim3 gae((NE + 7) / 8);                   // 1250
  const dim3 gan((NN + 7) / 8);                   // 6250

  // encode: h1 = relu(X@W0+b0) ; z = h1@W1+b1 -> split zhi/zlo
  to_bf16_kernel<<<(NN * OBSD / 4 + 255) / 256, 256, 0, stream>>>(X, k2b, NN * OBSD);
  gemm_kernel<EPI_RELU_BF16><<<g50, blk, 0, stream>>>(k2b, encW0T, encb0, NN, LATD, OBSD,
                                                      k1b, nullptr, nullptr);
  gemm_kernel<EPI_SPLIT><<<g50, blk, 0, stream>>>(k1b, encW1T, encb1, NN, LATD, LATD,
                                                  zhi, zlo, nullptr);

  // RK4: per substep  agg_e -> edge GEMM (Wc) -> fused node-gather+epilogue
  for (int s = 0; s < NSTEPS; ++s) {
    for (int k = 0; k < 4; ++k) {
      const u16* src = (k == 0) ? zhi : (k == 1) ? k1b : (k == 2) ? k2b : k3b;
      agg_kernel<<<gae, blk, 0, stream>>>(src, off_e, lst_e, recip_e, eagg, NE);
      gemm_kernel<EPI_BF16><<<g10, blk, 0, stream>>>(eagg, WcT, zeros, NE, LATD, LATD,
                                                     G, nullptr, nullptr);
      if (k == 0)
        aggn_epi_kernel<0><<<gan, blk, 0, stream>>>(G, off_n, lst_n, recip_n, dvec,
                                                    ub, k1b, k2b, k3b, zhi, zlo, 0.f);
      else if (k == 1)
        aggn_epi_kernel<1><<<gan, blk, 0, stream>>>(G, off_n, lst_n, recip_n, dvec,
                                                    ub, k1b, k2b, k3b, zhi, zlo, 0.0625f);
      else if (k == 2)
        aggn_epi_kernel<2><<<gan, blk, 0, stream>>>(G, off_n, lst_n, recip_n, dvec,
                                                    ub, k1b, k2b, k3b, zhi, zlo, 0.0625f);
      else
        aggn_epi_kernel<3><<<gan, blk, 0, stream>>>(G, off_n, lst_n, recip_n, dvec,
                                                    ub, k1b, k2b, k3b, zhi, zlo, 0.125f);
    }
  }

  // decode (zhi = bf16(z_final))
  gemm_kernel<EPI_RELU_BF16><<<g50, blk, 0, stream>>>(zhi, decW0T, decb0, NN, LATD, LATD,
                                                      k1b, nullptr, nullptr);
  gemm_kernel<EPI_F32><<<gdec, blk, 0, stream>>>(k1b, decW1T, decb1, NN, OBSD, LATD,
                                                 nullptr, nullptr, out);
}

// Round 6
// 2041.557 us; speedup vs baseline: 2.8675x; 1.0772x over previous
//
#include <hip/hip_runtime.h>

#define NN 50000
#define NE 10000
#define NNZC 200000
#define OBSD 128
#define LATD 256
#define NSTEPS 8

typedef unsigned short u16;
typedef unsigned char u8;
typedef __attribute__((ext_vector_type(8))) short bf16x8;
typedef __attribute__((ext_vector_type(4))) float f32x4;
typedef __attribute__((ext_vector_type(2))) float f32x2;
typedef __attribute__((ext_vector_type(4))) u16 us4;
typedef __attribute__((ext_vector_type(8))) u16 us8;
typedef __attribute__((ext_vector_type(2))) unsigned int u32x2;

__device__ __forceinline__ u16 f2b(float f) {
  unsigned int u = __builtin_bit_cast(unsigned int, f);
  u = (u + 0x7FFFu + ((u >> 16) & 1u)) >> 16;
  return (u16)u;
}
__device__ __forceinline__ float b2f(u16 h) {
  unsigned int u = ((unsigned int)h) << 16;
  return __builtin_bit_cast(float, u);
}
__device__ __forceinline__ float fast_tanh(float x) {
  float e = __expf(2.0f * x);
  return 1.0f - 2.0f / (e + 1.0f);
}

// ---- OCP e4m3 fp8 pack/unpack (HW converts, gfx950) ----
__device__ __forceinline__ void fp8_decode8(u32x2 w, float* o) {
  f32x2 a = __builtin_amdgcn_cvt_pk_f32_fp8((int)w[0], false);
  f32x2 b = __builtin_amdgcn_cvt_pk_f32_fp8((int)w[0], true);
  f32x2 c = __builtin_amdgcn_cvt_pk_f32_fp8((int)w[1], false);
  f32x2 d = __builtin_amdgcn_cvt_pk_f32_fp8((int)w[1], true);
  o[0] = a[0]; o[1] = a[1]; o[2] = b[0]; o[3] = b[1];
  o[4] = c[0]; o[5] = c[1]; o[6] = d[0]; o[7] = d[1];
}
__device__ __forceinline__ u32x2 fp8_encode8(const float* v) {
  int lo = __builtin_amdgcn_cvt_pk_fp8_f32(v[0], v[1], 0, false);
  lo = __builtin_amdgcn_cvt_pk_fp8_f32(v[2], v[3], lo, true);
  int hi = __builtin_amdgcn_cvt_pk_fp8_f32(v[4], v[5], 0, false);
  hi = __builtin_amdgcn_cvt_pk_fp8_f32(v[6], v[7], hi, true);
  u32x2 r;
  r[0] = (unsigned int)lo;
  r[1] = (unsigned int)hi;
  return r;
}

typedef __attribute__((address_space(1))) const unsigned int GU32;
typedef __attribute__((address_space(3))) unsigned int LU32;
__device__ __forceinline__ void async16(const void* g, void* l) {
  __builtin_amdgcn_global_load_lds((GU32*)g, (LU32*)l, 16, 0, 0);
}

// ---------------- CSR build ----------------

__global__ void count_kernel(const int* __restrict__ ni, const int* __restrict__ ei,
                             int* __restrict__ cnt_n, int* __restrict__ cnt_e, int nnz) {
  int i = blockIdx.x * blockDim.x + threadIdx.x;
  if (i < nnz) {
    atomicAdd(&cnt_n[ni[i]], 1);
    atomicAdd(&cnt_e[ei[i]], 1);
  }
}

__global__ __launch_bounds__(1024) void scan1_kernel(const int* __restrict__ cnt,
                                                     int* __restrict__ off,
                                                     int* __restrict__ bsum, int n) {
  __shared__ int ws[16];
  const int tid = threadIdx.x;
  const int lane = tid & 63, w = tid >> 6;
  const int i = blockIdx.x * 1024 + tid;
  int v = (i < n) ? cnt[i] : 0;
  int s = v;
#pragma unroll
  for (int d = 1; d < 64; d <<= 1) {
    int t2 = __shfl_up(s, d);
    if (lane >= d) s += t2;
  }
  if (lane == 63) ws[w] = s;
  __syncthreads();
  if (w == 0) {
    int x = (lane < 16) ? ws[lane] : 0;
#pragma unroll
    for (int d = 1; d < 16; d <<= 1) {
      int t2 = __shfl_up(x, d);
      if (lane >= d) x += t2;
    }
    if (lane < 16) ws[lane] = x;
  }
  __syncthreads();
  const int base = w ? ws[w - 1] : 0;
  if (i < n) off[i] = base + s - v;
  if (tid == 0) bsum[blockIdx.x] = ws[15];
}

__global__ void scan2_kernel(int* __restrict__ bsum, int nb) {
  const int lane = threadIdx.x;
  int v = (lane < nb) ? bsum[lane] : 0;
  int s = v;
#pragma unroll
  for (int d = 1; d < 64; d <<= 1) {
    int t2 = __shfl_up(s, d);
    if (lane >= d) s += t2;
  }
  if (lane < nb) bsum[lane] = s - v;
  if (lane == 63) bsum[nb] = s;
}

__global__ void scan3_kernel(const int* __restrict__ cnt, int* __restrict__ off,
                             int* __restrict__ cur, float* __restrict__ recip,
                             const int* __restrict__ bsum, int n) {
  const int i = blockIdx.x * blockDim.x + threadIdx.x;
  if (i < n) {
    const int o = off[i] + bsum[i >> 10];
    off[i] = o;
    cur[i] = o;
    recip[i] = 1.0f / fmaxf((float)cnt[i], 1.0f);
  }
  if (i == 0) off[n] = bsum[(n + 1023) >> 10];
}

__global__ void fill_kernel(const int* __restrict__ ni, const int* __restrict__ ei,
                            int* __restrict__ cur_n, int* __restrict__ cur_e,
                            int* __restrict__ lst_n, int* __restrict__ lst_e, int nnz) {
  int i = blockIdx.x * blockDim.x + threadIdx.x;
  if (i < nnz) {
    int n = ni[i], e = ei[i];
    lst_e[atomicAdd(&cur_e[e], 1)] = n;
    lst_n[atomicAdd(&cur_n[n], 1)] = e;
  }
}

// ---------------- small prep ----------------

__global__ void transpose_kernel(const float* __restrict__ W, u16* __restrict__ WT, int K, int N) {
  int i = blockIdx.x * blockDim.x + threadIdx.x;
  if (i >= K * N) return;
  int k = i / N, n = i - k * N;
  WT[n * K + k] = f2b(W[i]);
}

__global__ void to_bf16_kernel(const float* __restrict__ src, u16* __restrict__ dst, int n) {
  int i = (blockIdx.x * blockDim.x + threadIdx.x) * 4;
  if (i >= n) return;
  float4 v = *reinterpret_cast<const float4*>(src + i);
  us4 o;
  o.x = f2b(v.x); o.y = f2b(v.y); o.z = f2b(v.z); o.w = f2b(v.w);
  *reinterpret_cast<us4*>(dst + i) = o;
}

// d = bne @ Wen + ben
__global__ void dvec_kernel(const float* __restrict__ bne, const float* __restrict__ Wen,
                            const float* __restrict__ ben, float* __restrict__ d) {
  const int j = threadIdx.x;
  float s = ben[j];
  for (int k = 0; k < LATD; ++k) s += bne[k] * Wen[k * LATD + j];
  d[j] = s;
}

// ---------------- edge segment mean: 2 segments/wave ----------------
// FP8SRC=0: bf16 source rows; FP8SRC=1: fp8(e4m3) source rows. Output bf16.

template <int FP8SRC>
__global__ __launch_bounds__(256) void agg_kernel(const void* __restrict__ src,
                                                  const int* __restrict__ off,
                                                  const int* __restrict__ lst,
                                                  const float* __restrict__ recip,
                                                  u16* __restrict__ dst, int nseg) {
  const int t = threadIdx.x;
  const int cl = t & 31;
  const int seg = blockIdx.x * 8 + (t >> 5);
  if (seg >= nseg) return;
  const int s = off[seg], e = off[seg + 1];
  float a[8] = {};
  for (int p = s; p < e; ++p) {
    const int r = lst[p];
    if constexpr (FP8SRC) {
      u32x2 w = *(const u32x2*)((const u8*)src + (size_t)r * LATD + cl * 8);
      float f[8];
      fp8_decode8(w, f);
#pragma unroll
      for (int j = 0; j < 8; ++j) a[j] += f[j];
    } else {
      us8 v = *(reinterpret_cast<const us8*>((const u16*)src + (size_t)r * LATD) + cl);
#pragma unroll
      for (int j = 0; j < 8; ++j) a[j] += b2f(v[j]);
    }
  }
  const float rc = recip[seg];
  us8 o;
#pragma unroll
  for (int j = 0; j < 8; ++j) o[j] = f2b(a[j] * rc);
  *(reinterpret_cast<us8*>(dst + (size_t)seg * LATD) + cl) = o;
}

// ---------------- fused node-gather + RK epilogue (streaming, no LDS) ----------------
// STAGE 0: u = mean + d; k1 = tanh(u); write u, k1(bf16), k(fp8)
// STAGE 1/2: k_i = tanh(u + c*mean); write k_i(bf16), k(fp8)
// STAGE 3: k4 = tanh(u + c*mean); z += dt/6*(k1+2k2+2k3+k4); write zhi(bf16)

template <int FP8G, int STAGE>
__global__ __launch_bounds__(256) void aggn_epi_kernel(
    const void* __restrict__ G, const int* __restrict__ off, const int* __restrict__ lst,
    const float* __restrict__ recip, const float* __restrict__ dvec,
    u16* __restrict__ ub, u16* __restrict__ k1b, u16* __restrict__ k2b,
    u16* __restrict__ k3b, u8* __restrict__ kf8, u16* __restrict__ zhi, float c) {
  const int t = threadIdx.x;
  const int cl = t & 31;
  const int node = blockIdx.x * 8 + (t >> 5);
  if (node >= NN) return;
  const int s = off[node], e = off[node + 1];
  float v[8] = {};
  for (int p = s; p < e; ++p) {
    const int er = lst[p];
    if constexpr (FP8G) {
      u32x2 w = *(const u32x2*)((const u8*)G + (size_t)er * LATD + cl * 8);
      float f[8];
      fp8_decode8(w, f);
#pragma unroll
      for (int j = 0; j < 8; ++j) v[j] += f[j];
    } else {
      us8 g = *(reinterpret_cast<const us8*>((const u16*)G + (size_t)er * LATD) + cl);
#pragma unroll
      for (int j = 0; j < 8; ++j) v[j] += b2f(g[j]);
    }
  }
  const float rc = recip[node];
  const size_t base = (size_t)node * LATD + cl * 8;
  const float dt6 = 0.125f / 6.0f;

  if constexpr (STAGE == 0) {
    float kv[8];
    us8 uo, ko;
#pragma unroll
    for (int j = 0; j < 8; ++j) {
      const float u = v[j] * rc + dvec[cl * 8 + j];
      uo[j] = f2b(u);
      kv[j] = fast_tanh(u);
      ko[j] = f2b(kv[j]);
    }
    *(us8*)(ub + base) = uo;
    *(us8*)(k1b + base) = ko;
    *(u32x2*)(kf8 + base) = fp8_encode8(kv);
  } else if constexpr (STAGE == 1 || STAGE == 2) {
    us8 uv = *(const us8*)(ub + base);
    float kv[8];
    us8 ko;
#pragma unroll
    for (int j = 0; j < 8; ++j) {
      kv[j] = fast_tanh(b2f(uv[j]) + c * (v[j] * rc));
      ko[j] = f2b(kv[j]);
    }
    *(us8*)((STAGE == 1 ? k2b : k3b) + base) = ko;
    *(u32x2*)(kf8 + base) = fp8_encode8(kv);
  } else {
    us8 uv = *(const us8*)(ub + base);
    us8 a1 = *(const us8*)(k1b + base);
    us8 a2 = *(const us8*)(k2b + base);
    us8 a3 = *(const us8*)(k3b + base);
    us8 zh = *(const us8*)(zhi + base);
    us8 ho;
#pragma unroll
    for (int j = 0; j < 8; ++j) {
      const float k4 = fast_tanh(b2f(uv[j]) + c * (v[j] * rc));
      const float zn = b2f(zh[j])
                     + dt6 * (b2f(a1[j]) + 2.0f * b2f(a2[j]) + 2.0f * b2f(a3[j]) + k4);
      ho[j] = f2b(zn);
    }
    *(us8*)(zhi + base) = ho;
  }
}

// ---------------- MFMA GEMM with LDS-staged coalesced epilogue ----------------

enum { EPI_RELU_BF16, EPI_BF16, EPI_F32, EPI_FP8 };

template <int MODE>
__global__ __launch_bounds__(256) void gemm_kernel(
    const u16* __restrict__ A, const u16* __restrict__ BT, const float* __restrict__ bias,
    int M, int N, int K,
    u16* __restrict__ outb, u8* __restrict__ outf8, float* __restrict__ outf) {
  __shared__ char smem[4 * 16 * 66 * 4];  // 16896B; GEMM phase uses first 16KB
  u16* lA = (u16*)smem;
  u16* lB = (u16*)(smem + 8192);
  const int t = threadIdx.x;
  const int m0 = blockIdx.x * 128, n0 = blockIdx.y * 128;
  const int srow = t >> 2;
  const int gslot = (t & 3) ^ ((srow >> 1) & 3);

  int ar0 = m0 + srow;      if (ar0 > M - 1) ar0 = M - 1;
  int ar1 = m0 + srow + 64; if (ar1 > M - 1) ar1 = M - 1;
  const u16* gA0 = A + (size_t)ar0 * K + gslot * 8;
  const u16* gA1 = A + (size_t)ar1 * K + gslot * 8;
  const u16* gB0 = BT + (size_t)(n0 + srow) * K + gslot * 8;
  const u16* gB1 = BT + (size_t)(n0 + srow + 64) * K + gslot * 8;
  char* lAd0 = (char*)lA + t * 16; char* lAd1 = lAd0 + 4096;
  char* lBd0 = (char*)lB + t * 16; char* lBd1 = lBd0 + 4096;

  const int lane = t & 63, wid = t >> 6;
  const int wm = wid >> 1, wn = wid & 1;
  const int lrow = lane & 15, kg = lane >> 4;

  f32x4 acc[4][4] = {};
  const char* lAb = (const char*)lA;
  const char* lBb = (const char*)lB;

  for (int kk = 0; kk < K; kk += 32) {
    async16(gA0 + kk, lAd0);
    async16(gA1 + kk, lAd1);
    async16(gB0 + kk, lBd0);
    async16(gB1 + kk, lBd1);
    __syncthreads();
    bf16x8 af[4], bg[4];
#pragma unroll
    for (int i = 0; i < 4; ++i) {
      int rA = wm * 64 + i * 16 + lrow;
      af[i] = *(const bf16x8*)(lAb + rA * 64 + (((kg ^ (rA >> 1)) & 3) << 4));
      int rB = wn * 64 + i * 16 + lrow;
      bg[i] = *(const bf16x8*)(lBb + rB * 64 + (((kg ^ (rB >> 1)) & 3) << 4));
    }
#pragma unroll
    for (int i = 0; i < 4; ++i)
#pragma unroll
      for (int j = 0; j < 4; ++j)
        acc[i][j] = __builtin_amdgcn_mfma_f32_16x16x32_bf16(af[i], bg[j], acc[i][j], 0, 0, 0);
    __syncthreads();
  }

  // staged epilogue (wave-private LDS region)
  float* stage = (float*)smem + wid * (16 * 66);
  const int rr = lane >> 3;
  const int c0 = (lane & 7) * 8;

#pragma unroll
  for (int ti = 0; ti < 4; ++ti) {
#pragma unroll
    for (int tj = 0; tj < 4; ++tj) {
      const float bv = bias[n0 + wn * 64 + tj * 16 + lrow];
#pragma unroll
      for (int j = 0; j < 4; ++j)
        stage[(kg * 4 + j) * 66 + tj * 16 + lrow] = acc[ti][tj][j] + bv;
    }
#pragma unroll
    for (int pass = 0; pass < 2; ++pass) {
      const int r = pass * 8 + rr;
      const int gr = m0 + wm * 64 + ti * 16 + r;
      if (gr >= M) continue;
      const int gc = n0 + wn * 64 + c0;
      const size_t idx = (size_t)gr * N + gc;
      float v[8];
      *(float4*)v = *(const float4*)&stage[r * 66 + c0];
      *(float4*)(v + 4) = *(const float4*)&stage[r * 66 + c0 + 4];

      if constexpr (MODE == EPI_RELU_BF16 || MODE == EPI_BF16) {
        us8 o;
#pragma unroll
        for (int e2 = 0; e2 < 8; ++e2)
          o[e2] = f2b(MODE == EPI_RELU_BF16 ? fmaxf(v[e2], 0.0f) : v[e2]);
        *(us8*)(outb + idx) = o;
      } else if constexpr (MODE == EPI_F32) {
        *(float4*)(outf + idx) = *(float4*)v;
        *(float4*)(outf + idx + 4) = *(float4*)(v + 4);
      } else {  // EPI_FP8
        *(u32x2*)(outf8 + idx) = fp8_encode8(v);
      }
    }
  }
}

// ---------------- launch ----------------

extern "C" void kernel_launch(void* const* d_in, const int* in_sizes, int n_in,
                              void* d_out, int out_size, void* d_ws, size_t ws_size,
                              hipStream_t stream) {
  const float* X = (const float*)d_in[0];
  const float* encW0 = (const float*)d_in[1];
  const float* encb0 = (const float*)d_in[2];
  const float* encW1 = (const float*)d_in[3];
  const float* encb1 = (const float*)d_in[4];
  const float* Wne = (const float*)d_in[5];
  const float* bne = (const float*)d_in[6];
  const float* Wen = (const float*)d_in[7];
  const float* ben = (const float*)d_in[8];
  const float* decW0 = (const float*)d_in[9];
  const float* decb0 = (const float*)d_in[10];
  const float* decW1 = (const float*)d_in[11];
  const float* decb1 = (const float*)d_in[12];
  const int* node_idx = (const int*)d_in[13];
  const int* edge_idx = (const int*)d_in[14];
  float* out = (float*)d_out;

  char* p = (char*)d_ws;
  auto alloc = [&](size_t bytes) {
    char* r = p;
    p += (bytes + 255) & ~(size_t)255;
    return r;
  };
  u16* zhi      = (u16*)alloc((size_t)NN * LATD * 2);
  u16* ub       = (u16*)alloc((size_t)NN * LATD * 2);
  u16* k1b      = (u16*)alloc((size_t)NN * LATD * 2);   // also h1 in encode/decode
  u16* k2b      = (u16*)alloc((size_t)NN * LATD * 2);
  u16* k3b      = (u16*)alloc((size_t)NN * LATD * 2);
  u8*  kf8      = (u8*)alloc((size_t)NN * LATD);        // shared fp8 gather plane / bf16(X) scratch
  u16* eagg     = (u16*)alloc((size_t)NE * LATD * 2);
  u16* Gb       = (u16*)alloc((size_t)NE * LATD * 2);   // stage-0 G (bf16)
  u8*  Gf8      = (u8*)alloc((size_t)NE * LATD);        // stage-1..3 G (fp8)
  u16* encW0T   = (u16*)alloc((size_t)OBSD * LATD * 2);
  u16* encW1T   = (u16*)alloc((size_t)LATD * LATD * 2);
  u16* WneB     = (u16*)alloc((size_t)LATD * LATD * 2);
  u16* WenT     = (u16*)alloc((size_t)LATD * LATD * 2);
  u16* WcT      = (u16*)alloc((size_t)LATD * LATD * 2);
  u16* decW0T   = (u16*)alloc((size_t)LATD * LATD * 2);
  u16* decW1T   = (u16*)alloc((size_t)LATD * OBSD * 2);
  float* dvec   = (float*)alloc(LATD * 4);
  float* zeros  = (float*)alloc(LATD * 4);
  int* cnt      = (int*)alloc((size_t)(NE + NN) * 4);
  int* cnt_e = cnt; int* cnt_n = cnt + NE;
  int* off_e    = (int*)alloc((size_t)(NE + 1) * 4);
  int* off_n    = (int*)alloc((size_t)(NN + 1) * 4);
  int* cur_e    = (int*)alloc((size_t)NE * 4);
  int* cur_n    = (int*)alloc((size_t)NN * 4);
  int* lst_e    = (int*)alloc((size_t)NNZC * 4);
  int* lst_n    = (int*)alloc((size_t)NNZC * 4);
  float* recip_e = (float*)alloc((size_t)NE * 4);
  float* recip_n = (float*)alloc((size_t)NN * 4);
  int* bsum_e   = (int*)alloc(16 * 4);
  int* bsum_n   = (int*)alloc(64 * 4);

  size_t needed = (size_t)(p - (char*)d_ws);
  if (needed > ws_size) {
    hipMemsetAsync(d_out, 0x7F, (size_t)out_size * 4, stream);
    return;
  }

  const int nbe = (NE + 1023) / 1024, nbn = (NN + 1023) / 1024;

  // CSR build
  hipMemsetAsync(cnt, 0, (size_t)(NE + NN) * 4, stream);
  count_kernel<<<(NNZC + 255) / 256, 256, 0, stream>>>(node_idx, edge_idx, cnt_n, cnt_e, NNZC);
  scan1_kernel<<<nbe, 1024, 0, stream>>>(cnt_e, off_e, bsum_e, NE);
  scan1_kernel<<<nbn, 1024, 0, stream>>>(cnt_n, off_n, bsum_n, NN);
  scan2_kernel<<<1, 64, 0, stream>>>(bsum_e, nbe);
  scan2_kernel<<<1, 64, 0, stream>>>(bsum_n, nbn);
  scan3_kernel<<<(NE + 255) / 256, 256, 0, stream>>>(cnt_e, off_e, cur_e, recip_e, bsum_e, NE);
  scan3_kernel<<<(NN + 255) / 256, 256, 0, stream>>>(cnt_n, off_n, cur_n, recip_n, bsum_n, NN);
  fill_kernel<<<(NNZC + 255) / 256, 256, 0, stream>>>(node_idx, edge_idx, cur_n, cur_e, lst_n, lst_e, NNZC);

  // weight prep
  transpose_kernel<<<(OBSD * LATD + 255) / 256, 256, 0, stream>>>(encW0, encW0T, OBSD, LATD);
  transpose_kernel<<<(LATD * LATD + 255) / 256, 256, 0, stream>>>(encW1, encW1T, LATD, LATD);
  transpose_kernel<<<(LATD * LATD + 255) / 256, 256, 0, stream>>>(Wen, WenT, LATD, LATD);
  transpose_kernel<<<(LATD * LATD + 255) / 256, 256, 0, stream>>>(decW0, decW0T, LATD, LATD);
  transpose_kernel<<<(LATD * OBSD + 255) / 256, 256, 0, stream>>>(decW1, decW1T, LATD, OBSD);
  to_bf16_kernel<<<(LATD * LATD / 4 + 255) / 256, 256, 0, stream>>>(Wne, WneB, LATD * LATD);
  hipMemsetAsync(zeros, 0, LATD * 4, stream);
  dvec_kernel<<<1, LATD, 0, stream>>>(bne, Wen, ben, dvec);
  gemm_kernel<EPI_BF16><<<dim3(2, 2), 256, 0, stream>>>(WenT, WneB, zeros, LATD, LATD, LATD,
                                                        WcT, nullptr, nullptr);

  const dim3 blk(256);
  const dim3 g50((NN + 127) / 128, LATD / 128);   // (391, 2)
  const dim3 g10((NE + 127) / 128, LATD / 128);   // (79, 2)
  const dim3 gdec((NN + 127) / 128, OBSD / 128);  // (391, 1)
  const dim3 gae((NE + 7) / 8);                   // 1250
  const dim3 gan((NN + 7) / 8);                   // 6250

  // encode: h1 = relu(X@W0+b0) ; z = h1@W1+b1 -> zhi (bf16)
  to_bf16_kernel<<<(NN * OBSD / 4 + 255) / 256, 256, 0, stream>>>(X, (u16*)kf8, NN * OBSD);
  gemm_kernel<EPI_RELU_BF16><<<g50, blk, 0, stream>>>((u16*)kf8, encW0T, encb0, NN, LATD, OBSD,
                                                      k1b, nullptr, nullptr);
  gemm_kernel<EPI_BF16><<<g50, blk, 0, stream>>>(k1b, encW1T, encb1, NN, LATD, LATD,
                                                 zhi, nullptr, nullptr);

  // RK4: per substep  agg_e -> edge GEMM (Wc) -> fused node-gather+epilogue
  for (int s = 0; s < NSTEPS; ++s) {
    for (int k = 0; k < 4; ++k) {
      if (k == 0) {
        agg_kernel<0><<<gae, blk, 0, stream>>>(zhi, off_e, lst_e, recip_e, eagg, NE);
        gemm_kernel<EPI_BF16><<<g10, blk, 0, stream>>>(eagg, WcT, zeros, NE, LATD, LATD,
                                                       Gb, nullptr, nullptr);
        aggn_epi_kernel<0, 0><<<gan, blk, 0, stream>>>(Gb, off_n, lst_n, recip_n, dvec,
                                                       ub, k1b, k2b, k3b, kf8, zhi, 0.f);
      } else {
        agg_kernel<1><<<gae, blk, 0, stream>>>(kf8, off_e, lst_e, recip_e, eagg, NE);
        gemm_kernel<EPI_FP8><<<g10, blk, 0, stream>>>(eagg, WcT, zeros, NE, LATD, LATD,
                                                      nullptr, Gf8, nullptr);
        if (k == 1)
          aggn_epi_kernel<1, 1><<<gan, blk, 0, stream>>>(Gf8, off_n, lst_n, recip_n, dvec,
                                                         ub, k1b, k2b, k3b, kf8, zhi, 0.0625f);
        else if (k == 2)
          aggn_epi_kernel<1, 2><<<gan, blk, 0, stream>>>(Gf8, off_n, lst_n, recip_n, dvec,
                                                         ub, k1b, k2b, k3b, kf8, zhi, 0.0625f);
        else
          aggn_epi_kernel<1, 3><<<gan, blk, 0, stream>>>(Gf8, off_n, lst_n, recip_n, dvec,
                                                         ub, k1b, k2b, k3b, kf8, zhi, 0.125f);
      }
    }
  }

  // decode (zhi = bf16(z_final))
  gemm_kernel<EPI_RELU_BF16><<<g50, blk, 0, stream>>>(zhi, decW0T, decb0, NN, LATD, LATD,
                                                      k1b, nullptr, nullptr);
  gemm_kernel<EPI_F32><<<gdec, blk, 0, stream>>>(k1b, decW1T, decb1, NN, OBSD, LATD,
                                                 nullptr, nullptr, out);
}

// Round 7
// 2022.396 us; speedup vs baseline: 2.8947x; 1.0095x over previous
//
#include <hip/hip_runtime.h>

#define NN 50000
#define NE 10000
#define NNZC 200000
#define OBSD 128
#define LATD 256
#define NSTEPS 8

typedef unsigned short u16;
typedef unsigned char u8;
typedef __attribute__((ext_vector_type(8))) short bf16x8;
typedef __attribute__((ext_vector_type(4))) float f32x4;
typedef __attribute__((ext_vector_type(2))) float f32x2;
typedef __attribute__((ext_vector_type(4))) u16 us4;
typedef __attribute__((ext_vector_type(8))) u16 us8;
typedef __attribute__((ext_vector_type(16))) u16 us16;
typedef __attribute__((ext_vector_type(2))) unsigned int u32x2;
typedef __attribute__((ext_vector_type(4))) unsigned int u32x4;

__device__ __forceinline__ u16 f2b(float f) {
  unsigned int u = __builtin_bit_cast(unsigned int, f);
  u = (u + 0x7FFFu + ((u >> 16) & 1u)) >> 16;
  return (u16)u;
}
__device__ __forceinline__ float b2f(u16 h) {
  unsigned int u = ((unsigned int)h) << 16;
  return __builtin_bit_cast(float, u);
}
__device__ __forceinline__ float fast_tanh(float x) {
  float e = __expf(2.0f * x);
  return 1.0f - 2.0f / (e + 1.0f);
}

// ---- OCP e4m3 fp8 pack/unpack (HW converts, gfx950) ----
__device__ __forceinline__ void fp8_dec4(unsigned int w, float* o) {
  f32x2 a = __builtin_amdgcn_cvt_pk_f32_fp8((int)w, false);
  f32x2 b = __builtin_amdgcn_cvt_pk_f32_fp8((int)w, true);
  o[0] = a[0]; o[1] = a[1]; o[2] = b[0]; o[3] = b[1];
}
__device__ __forceinline__ unsigned int fp8_enc4(const float* v) {
  int lo = __builtin_amdgcn_cvt_pk_fp8_f32(v[0], v[1], 0, false);
  lo = __builtin_amdgcn_cvt_pk_fp8_f32(v[2], v[3], lo, true);
  return (unsigned int)lo;
}

typedef __attribute__((address_space(1))) const unsigned int GU32;
typedef __attribute__((address_space(3))) unsigned int LU32;
__device__ __forceinline__ void async16(const void* g, void* l) {
  __builtin_amdgcn_global_load_lds((GU32*)g, (LU32*)l, 16, 0, 0);
}

// ---------------- CSR build ----------------

__global__ void count_kernel(const int* __restrict__ ni, const int* __restrict__ ei,
                             int* __restrict__ cnt_n, int* __restrict__ cnt_e, int nnz) {
  int i = blockIdx.x * blockDim.x + threadIdx.x;
  if (i < nnz) {
    atomicAdd(&cnt_n[ni[i]], 1);
    atomicAdd(&cnt_e[ei[i]], 1);
  }
}

__global__ __launch_bounds__(1024) void scan1_kernel(const int* __restrict__ cnt,
                                                     int* __restrict__ off,
                                                     int* __restrict__ bsum, int n) {
  __shared__ int ws[16];
  const int tid = threadIdx.x;
  const int lane = tid & 63, w = tid >> 6;
  const int i = blockIdx.x * 1024 + tid;
  int v = (i < n) ? cnt[i] : 0;
  int s = v;
#pragma unroll
  for (int d = 1; d < 64; d <<= 1) {
    int t2 = __shfl_up(s, d);
    if (lane >= d) s += t2;
  }
  if (lane == 63) ws[w] = s;
  __syncthreads();
  if (w == 0) {
    int x = (lane < 16) ? ws[lane] : 0;
#pragma unroll
    for (int d = 1; d < 16; d <<= 1) {
      int t2 = __shfl_up(x, d);
      if (lane >= d) x += t2;
    }
    if (lane < 16) ws[lane] = x;
  }
  __syncthreads();
  const int base = w ? ws[w - 1] : 0;
  if (i < n) off[i] = base + s - v;
  if (tid == 0) bsum[blockIdx.x] = ws[15];
}

__global__ void scan2_kernel(int* __restrict__ bsum, int nb) {
  const int lane = threadIdx.x;
  int v = (lane < nb) ? bsum[lane] : 0;
  int s = v;
#pragma unroll
  for (int d = 1; d < 64; d <<= 1) {
    int t2 = __shfl_up(s, d);
    if (lane >= d) s += t2;
  }
  if (lane < nb) bsum[lane] = s - v;
  if (lane == 63) bsum[nb] = s;
}

__global__ void scan3_kernel(const int* __restrict__ cnt, int* __restrict__ off,
                             int* __restrict__ cur, float* __restrict__ recip,
                             const int* __restrict__ bsum, int n) {
  const int i = blockIdx.x * blockDim.x + threadIdx.x;
  if (i < n) {
    const int o = off[i] + bsum[i >> 10];
    off[i] = o;
    cur[i] = o;
    recip[i] = 1.0f / fmaxf((float)cnt[i], 1.0f);
  }
  if (i == 0) off[n] = bsum[(n + 1023) >> 10];
}

__global__ void fill_kernel(const int* __restrict__ ni, const int* __restrict__ ei,
                            int* __restrict__ cur_n, int* __restrict__ cur_e,
                            int* __restrict__ lst_n, int* __restrict__ lst_e, int nnz) {
  int i = blockIdx.x * blockDim.x + threadIdx.x;
  if (i < nnz) {
    int n = ni[i], e = ei[i];
    lst_e[atomicAdd(&cur_e[e], 1)] = n;
    lst_n[atomicAdd(&cur_n[n], 1)] = e;
  }
}

// ---------------- small prep ----------------

__global__ void transpose_kernel(const float* __restrict__ W, u16* __restrict__ WT, int K, int N) {
  int i = blockIdx.x * blockDim.x + threadIdx.x;
  if (i >= K * N) return;
  int k = i / N, n = i - k * N;
  WT[n * K + k] = f2b(W[i]);
}

__global__ void to_bf16_kernel(const float* __restrict__ src, u16* __restrict__ dst, int n) {
  int i = (blockIdx.x * blockDim.x + threadIdx.x) * 4;
  if (i >= n) return;
  float4 v = *reinterpret_cast<const float4*>(src + i);
  us4 o;
  o.x = f2b(v.x); o.y = f2b(v.y); o.z = f2b(v.z); o.w = f2b(v.w);
  *reinterpret_cast<us4*>(dst + i) = o;
}

// d = bne @ Wen + ben
__global__ void dvec_kernel(const float* __restrict__ bne, const float* __restrict__ Wen,
                            const float* __restrict__ ben, float* __restrict__ d) {
  const int j = threadIdx.x;
  float s = ben[j];
  for (int k = 0; k < LATD; ++k) s += bne[k] * Wen[k * LATD + j];
  d[j] = s;
}

// ---------------- edge segment mean ----------------
// FP8SRC=1: fp8 rows (256B), 16-lane groups, 16 elems/lane.
// FP8SRC=0: bf16 rows (512B), 32-lane groups, 8 elems/lane. Output bf16.

template <int FP8SRC>
__global__ __launch_bounds__(256) void agg_kernel(const void* __restrict__ src,
                                                  const int* __restrict__ off,
                                                  const int* __restrict__ lst,
                                                  const float* __restrict__ recip,
                                                  u16* __restrict__ dst, int nseg) {
  constexpr int GW = FP8SRC ? 16 : 32;
  constexpr int EPL = LATD / GW;  // 16 or 8
  const int t = threadIdx.x;
  const int gl = t & (GW - 1);
  const int seg = blockIdx.x * (256 / GW) + (t / GW);
  if (seg >= nseg) return;
  const int s = off[seg], e = off[seg + 1];
  float a[EPL] = {};
  for (int p = s; p < e; ++p) {
    const int r = lst[p];
    if constexpr (FP8SRC) {
      u32x4 w = *(const u32x4*)((const u8*)src + (size_t)r * LATD + gl * 16);
      float f[16];
#pragma unroll
      for (int q = 0; q < 4; ++q) fp8_dec4(w[q], f + q * 4);
#pragma unroll
      for (int j = 0; j < 16; ++j) a[j] += f[j];
    } else {
      us8 v = *(const us8*)((const u16*)src + (size_t)r * LATD + gl * 8);
#pragma unroll
      for (int j = 0; j < 8; ++j) a[j] += b2f(v[j]);
    }
  }
  const float rc = recip[seg];
  const size_t base = (size_t)seg * LATD + gl * EPL;
  if constexpr (FP8SRC) {
    us16 o;
#pragma unroll
    for (int j = 0; j < 16; ++j) o[j] = f2b(a[j] * rc);
    *(us16*)(dst + base) = o;
  } else {
    us8 o;
#pragma unroll
    for (int j = 0; j < 8; ++j) o[j] = f2b(a[j] * rc);
    *(us8*)(dst + base) = o;
  }
}

// ---------------- fused node-gather + RK epilogue ----------------
// STAGE 0 (bf16 G, 32-lane): u = mean + d; write ub(bf16), kf8=fp8(k1)   [no k1b!]
// STAGE 1/2 (fp8 G, 16-lane): k_i = tanh(u + c*mean); write k_i(bf16), kf8
// STAGE 3 (fp8 G, 16-lane): k1=tanh(u); k4=tanh(u+c*mean);
//                           z += dt/6*(k1+2k2+2k3+k4)

template <int STAGE>
__global__ __launch_bounds__(256) void aggn_epi_kernel(
    const void* __restrict__ G, const int* __restrict__ off, const int* __restrict__ lst,
    const float* __restrict__ recip, const float* __restrict__ dvec,
    u16* __restrict__ ub, u16* __restrict__ k2b, u16* __restrict__ k3b,
    u8* __restrict__ kf8, u16* __restrict__ zhi, float c) {
  constexpr int GW = (STAGE == 0) ? 32 : 16;
  constexpr int EPL = LATD / GW;  // 8 or 16
  const int t = threadIdx.x;
  const int gl = t & (GW - 1);
  const int node = blockIdx.x * (256 / GW) + (t / GW);
  if (node >= NN) return;
  const int s = off[node], e = off[node + 1];
  float v[EPL] = {};
  for (int p = s; p < e; ++p) {
    const int er = lst[p];
    if constexpr (STAGE == 0) {
      us8 g = *(const us8*)((const u16*)G + (size_t)er * LATD + gl * 8);
#pragma unroll
      for (int j = 0; j < 8; ++j) v[j] += b2f(g[j]);
    } else {
      u32x4 w = *(const u32x4*)((const u8*)G + (size_t)er * LATD + gl * 16);
      float f[16];
#pragma unroll
      for (int q = 0; q < 4; ++q) fp8_dec4(w[q], f + q * 4);
#pragma unroll
      for (int j = 0; j < 16; ++j) v[j] += f[j];
    }
  }
  const float rc = recip[node];
  const size_t base = (size_t)node * LATD + gl * EPL;
  const float dt6 = 0.125f / 6.0f;

  if constexpr (STAGE == 0) {
    float kv[8];
    us8 uo;
#pragma unroll
    for (int j = 0; j < 8; ++j) {
      const float u = v[j] * rc + dvec[gl * 8 + j];
      uo[j] = f2b(u);
      kv[j] = fast_tanh(u);
    }
    *(us8*)(ub + base) = uo;
    u32x2 kp;
    kp[0] = fp8_enc4(kv);
    kp[1] = fp8_enc4(kv + 4);
    *(u32x2*)(kf8 + base) = kp;
  } else if constexpr (STAGE == 1 || STAGE == 2) {
    us16 uv = *(const us16*)(ub + base);
    float kv[16];
    us16 ko;
#pragma unroll
    for (int j = 0; j < 16; ++j) {
      kv[j] = fast_tanh(b2f(uv[j]) + c * (v[j] * rc));
      ko[j] = f2b(kv[j]);
    }
    *(us16*)((STAGE == 1 ? k2b : k3b) + base) = ko;
    u32x4 kp;
#pragma unroll
    for (int q = 0; q < 4; ++q) kp[q] = fp8_enc4(kv + q * 4);
    *(u32x4*)(kf8 + base) = kp;
  } else {
    us16 uv = *(const us16*)(ub + base);
    us16 a2 = *(const us16*)(k2b + base);
    us16 a3 = *(const us16*)(k3b + base);
    us16 zh = *(const us16*)(zhi + base);
    us16 ho;
#pragma unroll
    for (int j = 0; j < 16; ++j) {
      const float u = b2f(uv[j]);
      const float k1 = fast_tanh(u);
      const float k4 = fast_tanh(u + c * (v[j] * rc));
      const float zn = b2f(zh[j])
                     + dt6 * (k1 + 2.0f * b2f(a2[j]) + 2.0f * b2f(a3[j]) + k4);
      ho[j] = f2b(zn);
    }
    *(us16*)(zhi + base) = ho;
  }
}

// ---------------- MFMA GEMM with LDS-staged coalesced epilogue ----------------

enum { EPI_RELU_BF16, EPI_BF16, EPI_F32, EPI_FP8 };

template <int MODE>
__global__ __launch_bounds__(256) void gemm_kernel(
    const u16* __restrict__ A, const u16* __restrict__ BT, const float* __restrict__ bias,
    int M, int N, int K,
    u16* __restrict__ outb, u8* __restrict__ outf8, float* __restrict__ outf) {
  __shared__ char smem[4 * 16 * 66 * 4];  // 16896B; GEMM phase uses first 16KB
  u16* lA = (u16*)smem;
  u16* lB = (u16*)(smem + 8192);
  const int t = threadIdx.x;
  const int m0 = blockIdx.x * 128, n0 = blockIdx.y * 128;
  const int srow = t >> 2;
  const int gslot = (t & 3) ^ ((srow >> 1) & 3);

  int ar0 = m0 + srow;      if (ar0 > M - 1) ar0 = M - 1;
  int ar1 = m0 + srow + 64; if (ar1 > M - 1) ar1 = M - 1;
  const u16* gA0 = A + (size_t)ar0 * K + gslot * 8;
  const u16* gA1 = A + (size_t)ar1 * K + gslot * 8;
  const u16* gB0 = BT + (size_t)(n0 + srow) * K + gslot * 8;
  const u16* gB1 = BT + (size_t)(n0 + srow + 64) * K + gslot * 8;
  char* lAd0 = (char*)lA + t * 16; char* lAd1 = lAd0 + 4096;
  char* lBd0 = (char*)lB + t * 16; char* lBd1 = lBd0 + 4096;

  const int lane = t & 63, wid = t >> 6;
  const int wm = wid >> 1, wn = wid & 1;
  const int lrow = lane & 15, kg = lane >> 4;

  f32x4 acc[4][4] = {};
  const char* lAb = (const char*)lA;
  const char* lBb = (const char*)lB;

  for (int kk = 0; kk < K; kk += 32) {
    async16(gA0 + kk, lAd0);
    async16(gA1 + kk, lAd1);
    async16(gB0 + kk, lBd0);
    async16(gB1 + kk, lBd1);
    __syncthreads();
    bf16x8 af[4], bg[4];
#pragma unroll
    for (int i = 0; i < 4; ++i) {
      int rA = wm * 64 + i * 16 + lrow;
      af[i] = *(const bf16x8*)(lAb + rA * 64 + (((kg ^ (rA >> 1)) & 3) << 4));
      int rB = wn * 64 + i * 16 + lrow;
      bg[i] = *(const bf16x8*)(lBb + rB * 64 + (((kg ^ (rB >> 1)) & 3) << 4));
    }
#pragma unroll
    for (int i = 0; i < 4; ++i)
#pragma unroll
      for (int j = 0; j < 4; ++j)
        acc[i][j] = __builtin_amdgcn_mfma_f32_16x16x32_bf16(af[i], bg[j], acc[i][j], 0, 0, 0);
    __syncthreads();
  }

  // staged epilogue (wave-private LDS region)
  float* stage = (float*)smem + wid * (16 * 66);
  const int rr = lane >> 3;
  const int c0 = (lane & 7) * 8;

#pragma unroll
  for (int ti = 0; ti < 4; ++ti) {
#pragma unroll
    for (int tj = 0; tj < 4; ++tj) {
      const float bv = bias[n0 + wn * 64 + tj * 16 + lrow];
#pragma unroll
      for (int j = 0; j < 4; ++j)
        stage[(kg * 4 + j) * 66 + tj * 16 + lrow] = acc[ti][tj][j] + bv;
    }
#pragma unroll
    for (int pass = 0; pass < 2; ++pass) {
      const int r = pass * 8 + rr;
      const int gr = m0 + wm * 64 + ti * 16 + r;
      if (gr >= M) continue;
      const int gc = n0 + wn * 64 + c0;
      const size_t idx = (size_t)gr * N + gc;
      float v[8];
      *(float4*)v = *(const float4*)&stage[r * 66 + c0];
      *(float4*)(v + 4) = *(const float4*)&stage[r * 66 + c0 + 4];

      if constexpr (MODE == EPI_RELU_BF16 || MODE == EPI_BF16) {
        us8 o;
#pragma unroll
        for (int e2 = 0; e2 < 8; ++e2)
          o[e2] = f2b(MODE == EPI_RELU_BF16 ? fmaxf(v[e2], 0.0f) : v[e2]);
        *(us8*)(outb + idx) = o;
      } else if constexpr (MODE == EPI_F32) {
        *(float4*)(outf + idx) = *(float4*)v;
        *(float4*)(outf + idx + 4) = *(float4*)(v + 4);
      } else {  // EPI_FP8
        u32x2 kp;
        kp[0] = fp8_enc4(v);
        kp[1] = fp8_enc4(v + 4);
        *(u32x2*)(outf8 + idx) = kp;
      }
    }
  }
}

// ---------------- launch ----------------

extern "C" void kernel_launch(void* const* d_in, const int* in_sizes, int n_in,
                              void* d_out, int out_size, void* d_ws, size_t ws_size,
                              hipStream_t stream) {
  const float* X = (const float*)d_in[0];
  const float* encW0 = (const float*)d_in[1];
  const float* encb0 = (const float*)d_in[2];
  const float* encW1 = (const float*)d_in[3];
  const float* encb1 = (const float*)d_in[4];
  const float* Wne = (const float*)d_in[5];
  const float* bne = (const float*)d_in[6];
  const float* Wen = (const float*)d_in[7];
  const float* ben = (const float*)d_in[8];
  const float* decW0 = (const float*)d_in[9];
  const float* decb0 = (const float*)d_in[10];
  const float* decW1 = (const float*)d_in[11];
  const float* decb1 = (const float*)d_in[12];
  const int* node_idx = (const int*)d_in[13];
  const int* edge_idx = (const int*)d_in[14];
  float* out = (float*)d_out;

  char* p = (char*)d_ws;
  auto alloc = [&](size_t bytes) {
    char* r = p;
    p += (bytes + 255) & ~(size_t)255;
    return r;
  };
  u16* zhi      = (u16*)alloc((size_t)NN * LATD * 2);
  u16* ub       = (u16*)alloc((size_t)NN * LATD * 2);
  u16* k2b      = (u16*)alloc((size_t)NN * LATD * 2);
  u16* k3b      = (u16*)alloc((size_t)NN * LATD * 2);
  u16* h1b      = (u16*)alloc((size_t)NN * LATD * 2);   // encode/decode hidden
  u8*  kf8      = (u8*)alloc((size_t)NN * LATD);        // shared fp8 gather plane / bf16(X)
  u16* eagg     = (u16*)alloc((size_t)NE * LATD * 2);
  u16* Gb       = (u16*)alloc((size_t)NE * LATD * 2);   // stage-0 G (bf16)
  u8*  Gf8      = (u8*)alloc((size_t)NE * LATD);        // stage-1..3 G (fp8)
  u16* encW0T   = (u16*)alloc((size_t)OBSD * LATD * 2);
  u16* encW1T   = (u16*)alloc((size_t)LATD * LATD * 2);
  u16* WneB     = (u16*)alloc((size_t)LATD * LATD * 2);
  u16* WenT     = (u16*)alloc((size_t)LATD * LATD * 2);
  u16* WcT      = (u16*)alloc((size_t)LATD * LATD * 2);
  u16* decW0T   = (u16*)alloc((size_t)LATD * LATD * 2);
  u16* decW1T   = (u16*)alloc((size_t)LATD * OBSD * 2);
  float* dvec   = (float*)alloc(LATD * 4);
  float* zeros  = (float*)alloc(LATD * 4);
  int* cnt      = (int*)alloc((size_t)(NE + NN) * 4);
  int* cnt_e = cnt; int* cnt_n = cnt + NE;
  int* off_e    = (int*)alloc((size_t)(NE + 1) * 4);
  int* off_n    = (int*)alloc((size_t)(NN + 1) * 4);
  int* cur_e    = (int*)alloc((size_t)NE * 4);
  int* cur_n    = (int*)alloc((size_t)NN * 4);
  int* lst_e    = (int*)alloc((size_t)NNZC * 4);
  int* lst_n    = (int*)alloc((size_t)NNZC * 4);
  float* recip_e = (float*)alloc((size_t)NE * 4);
  float* recip_n = (float*)alloc((size_t)NN * 4);
  int* bsum_e   = (int*)alloc(16 * 4);
  int* bsum_n   = (int*)alloc(64 * 4);

  size_t needed = (size_t)(p - (char*)d_ws);
  if (needed > ws_size) {
    hipMemsetAsync(d_out, 0x7F, (size_t)out_size * 4, stream);
    return;
  }

  const int nbe = (NE + 1023) / 1024, nbn = (NN + 1023) / 1024;

  // CSR build
  hipMemsetAsync(cnt, 0, (size_t)(NE + NN) * 4, stream);
  count_kernel<<<(NNZC + 255) / 256, 256, 0, stream>>>(node_idx, edge_idx, cnt_n, cnt_e, NNZC);
  scan1_kernel<<<nbe, 1024, 0, stream>>>(cnt_e, off_e, bsum_e, NE);
  scan1_kernel<<<nbn, 1024, 0, stream>>>(cnt_n, off_n, bsum_n, NN);
  scan2_kernel<<<1, 64, 0, stream>>>(bsum_e, nbe);
  scan2_kernel<<<1, 64, 0, stream>>>(bsum_n, nbn);
  scan3_kernel<<<(NE + 255) / 256, 256, 0, stream>>>(cnt_e, off_e, cur_e, recip_e, bsum_e, NE);
  scan3_kernel<<<(NN + 255) / 256, 256, 0, stream>>>(cnt_n, off_n, cur_n, recip_n, bsum_n, NN);
  fill_kernel<<<(NNZC + 255) / 256, 256, 0, stream>>>(node_idx, edge_idx, cur_n, cur_e, lst_n, lst_e, NNZC);

  // weight prep
  transpose_kernel<<<(OBSD * LATD + 255) / 256, 256, 0, stream>>>(encW0, encW0T, OBSD, LATD);
  transpose_kernel<<<(LATD * LATD + 255) / 256, 256, 0, stream>>>(encW1, encW1T, LATD, LATD);
  transpose_kernel<<<(LATD * LATD + 255) / 256, 256, 0, stream>>>(Wen, WenT, LATD, LATD);
  transpose_kernel<<<(LATD * LATD + 255) / 256, 256, 0, stream>>>(decW0, decW0T, LATD, LATD);
  transpose_kernel<<<(LATD * OBSD + 255) / 256, 256, 0, stream>>>(decW1, decW1T, LATD, OBSD);
  to_bf16_kernel<<<(LATD * LATD / 4 + 255) / 256, 256, 0, stream>>>(Wne, WneB, LATD * LATD);
  hipMemsetAsync(zeros, 0, LATD * 4, stream);
  dvec_kernel<<<1, LATD, 0, stream>>>(bne, Wen, ben, dvec);
  gemm_kernel<EPI_BF16><<<dim3(2, 2), 256, 0, stream>>>(WenT, WneB, zeros, LATD, LATD, LATD,
                                                        WcT, nullptr, nullptr);

  const dim3 blk(256);
  const dim3 g50((NN + 127) / 128, LATD / 128);   // (391, 2)
  const dim3 g10((NE + 127) / 128, LATD / 128);   // (79, 2)
  const dim3 gdec((NN + 127) / 128, OBSD / 128);  // (391, 1)
  const dim3 gae32((NE + 7) / 8);                 // 1250 (bf16 src)
  const dim3 gae16((NE + 15) / 16);               // 625  (fp8 src)
  const dim3 gan32((NN + 7) / 8);                 // 6250 (stage 0)
  const dim3 gan16((NN + 15) / 16);               // 3125 (stages 1-3)

  // encode: h1 = relu(X@W0+b0) ; z = h1@W1+b1 -> zhi (bf16)
  to_bf16_kernel<<<(NN * OBSD / 4 + 255) / 256, 256, 0, stream>>>(X, (u16*)kf8, NN * OBSD);
  gemm_kernel<EPI_RELU_BF16><<<g50, blk, 0, stream>>>((u16*)kf8, encW0T, encb0, NN, LATD, OBSD,
                                                      h1b, nullptr, nullptr);
  gemm_kernel<EPI_BF16><<<g50, blk, 0, stream>>>(h1b, encW1T, encb1, NN, LATD, LATD,
                                                 zhi, nullptr, nullptr);

  // RK4: per substep  agg_e -> edge GEMM (Wc) -> fused node-gather+epilogue
  for (int s = 0; s < NSTEPS; ++s) {
    for (int k = 0; k < 4; ++k) {
      if (k == 0) {
        agg_kernel<0><<<gae32, blk, 0, stream>>>(zhi, off_e, lst_e, recip_e, eagg, NE);
        gemm_kernel<EPI_BF16><<<g10, blk, 0, stream>>>(eagg, WcT, zeros, NE, LATD, LATD,
                                                       Gb, nullptr, nullptr);
        aggn_epi_kernel<0><<<gan32, blk, 0, stream>>>(Gb, off_n, lst_n, recip_n, dvec,
                                                      ub, k2b, k3b, kf8, zhi, 0.f);
      } else {
        agg_kernel<1><<<gae16, blk, 0, stream>>>(kf8, off_e, lst_e, recip_e, eagg, NE);
        gemm_kernel<EPI_FP8><<<g10, blk, 0, stream>>>(eagg, WcT, zeros, NE, LATD, LATD,
                                                      nullptr, Gf8, nullptr);
        if (k == 1)
          aggn_epi_kernel<1><<<gan16, blk, 0, stream>>>(Gf8, off_n, lst_n, recip_n, dvec,
                                                        ub, k2b, k3b, kf8, zhi, 0.0625f);
        else if (k == 2)
          aggn_epi_kernel<2><<<gan16, blk, 0, stream>>>(Gf8, off_n, lst_n, recip_n, dvec,
                                                        ub, k2b, k3b, kf8, zhi, 0.0625f);
        else
          aggn_epi_kernel<3><<<gan16, blk, 0, stream>>>(Gf8, off_n, lst_n, recip_n, dvec,
                                                        ub, k2b, k3b, kf8, zhi, 0.125f);
      }
    }
  }

  // decode (zhi = bf16(z_final))
  gemm_kernel<EPI_RELU_BF16><<<g50, blk, 0, stream>>>(zhi, decW0T, decb0, NN, LATD, LATD,
                                                      h1b, nullptr, nullptr);
  gemm_kernel<EPI_F32><<<gdec, blk, 0, stream>>>(h1b, decW1T, decb1, NN, OBSD, LATD,
                                                 nullptr, nullptr, out);
}

// Round 8
// 1608.896 us; speedup vs baseline: 3.6387x; 1.2570x over previous
//
#include <hip/hip_runtime.h>

#define NN 50000
#define NE 10000
#define NNZC 200000
#define OBSD 128
#define LATD 256
#define NSTEPS 8

typedef unsigned short u16;
typedef unsigned char u8;
typedef __attribute__((ext_vector_type(8))) short bf16x8;
typedef __attribute__((ext_vector_type(4))) float f32x4;
typedef __attribute__((ext_vector_type(2))) float f32x2;
typedef __attribute__((ext_vector_type(4))) u16 us4;
typedef __attribute__((ext_vector_type(8))) u16 us8;
typedef __attribute__((ext_vector_type(16))) u16 us16;
typedef __attribute__((ext_vector_type(2))) unsigned int u32x2;
typedef __attribute__((ext_vector_type(4))) unsigned int u32x4;

__device__ __forceinline__ u16 f2b(float f) {
  unsigned int u = __builtin_bit_cast(unsigned int, f);
  u = (u + 0x7FFFu + ((u >> 16) & 1u)) >> 16;
  return (u16)u;
}
__device__ __forceinline__ float b2f(u16 h) {
  unsigned int u = ((unsigned int)h) << 16;
  return __builtin_bit_cast(float, u);
}
__device__ __forceinline__ float fast_tanh(float x) {
  float e = __expf(2.0f * x);
  return 1.0f - 2.0f / (e + 1.0f);
}

// ---- OCP e4m3 fp8 pack/unpack (HW converts, gfx950) ----
__device__ __forceinline__ void fp8_dec4(unsigned int w, float* o) {
  f32x2 a = __builtin_amdgcn_cvt_pk_f32_fp8((int)w, false);
  f32x2 b = __builtin_amdgcn_cvt_pk_f32_fp8((int)w, true);
  o[0] = a[0]; o[1] = a[1]; o[2] = b[0]; o[3] = b[1];
}
__device__ __forceinline__ void fp8_dec16(u32x4 w, float* o) {
#pragma unroll
  for (int q = 0; q < 4; ++q) fp8_dec4(w[q], o + q * 4);
}
__device__ __forceinline__ unsigned int fp8_enc4(const float* v) {
  int lo = __builtin_amdgcn_cvt_pk_fp8_f32(v[0], v[1], 0, false);
  lo = __builtin_amdgcn_cvt_pk_fp8_f32(v[2], v[3], lo, true);
  return (unsigned int)lo;
}

typedef __attribute__((address_space(1))) const unsigned int GU32;
typedef __attribute__((address_space(3))) unsigned int LU32;
__device__ __forceinline__ void async16(const void* g, void* l) {
  __builtin_amdgcn_global_load_lds((GU32*)g, (LU32*)l, 16, 0, 0);
}

// ---------------- CSR build ----------------

__global__ void count_kernel(const int* __restrict__ ni, const int* __restrict__ ei,
                             int* __restrict__ cnt_n, int* __restrict__ cnt_e, int nnz) {
  int i = blockIdx.x * blockDim.x + threadIdx.x;
  if (i < nnz) {
    atomicAdd(&cnt_n[ni[i]], 1);
    atomicAdd(&cnt_e[ei[i]], 1);
  }
}

__global__ __launch_bounds__(1024) void scan1_kernel(const int* __restrict__ cnt,
                                                     int* __restrict__ off,
                                                     int* __restrict__ bsum, int n) {
  __shared__ int ws[16];
  const int tid = threadIdx.x;
  const int lane = tid & 63, w = tid >> 6;
  const int i = blockIdx.x * 1024 + tid;
  int v = (i < n) ? cnt[i] : 0;
  int s = v;
#pragma unroll
  for (int d = 1; d < 64; d <<= 1) {
    int t2 = __shfl_up(s, d);
    if (lane >= d) s += t2;
  }
  if (lane == 63) ws[w] = s;
  __syncthreads();
  if (w == 0) {
    int x = (lane < 16) ? ws[lane] : 0;
#pragma unroll
    for (int d = 1; d < 16; d <<= 1) {
      int t2 = __shfl_up(x, d);
      if (lane >= d) x += t2;
    }
    if (lane < 16) ws[lane] = x;
  }
  __syncthreads();
  const int base = w ? ws[w - 1] : 0;
  if (i < n) off[i] = base + s - v;
  if (tid == 0) bsum[blockIdx.x] = ws[15];
}

__global__ void scan2_kernel(int* __restrict__ bsum, int nb) {
  const int lane = threadIdx.x;
  int v = (lane < nb) ? bsum[lane] : 0;
  int s = v;
#pragma unroll
  for (int d = 1; d < 64; d <<= 1) {
    int t2 = __shfl_up(s, d);
    if (lane >= d) s += t2;
  }
  if (lane < nb) bsum[lane] = s - v;
  if (lane == 63) bsum[nb] = s;
}

__global__ void scan3_kernel(const int* __restrict__ cnt, int* __restrict__ off,
                             int* __restrict__ cur, float* __restrict__ recip,
                             const int* __restrict__ bsum, int n) {
  const int i = blockIdx.x * blockDim.x + threadIdx.x;
  if (i < n) {
    const int o = off[i] + bsum[i >> 10];
    off[i] = o;
    cur[i] = o;
    recip[i] = 1.0f / fmaxf((float)cnt[i], 1.0f);
  }
  if (i == 0) off[n] = bsum[(n + 1023) >> 10];
}

__global__ void fill_kernel(const int* __restrict__ ni, const int* __restrict__ ei,
                            int* __restrict__ cur_n, int* __restrict__ cur_e,
                            int* __restrict__ lst_n, int* __restrict__ lst_e, int nnz) {
  int i = blockIdx.x * blockDim.x + threadIdx.x;
  if (i < nnz) {
    int n = ni[i], e = ei[i];
    lst_e[atomicAdd(&cur_e[e], 1)] = n;
    lst_n[atomicAdd(&cur_n[n], 1)] = e;
  }
}

// ---------------- small prep ----------------

__global__ void transpose_kernel(const float* __restrict__ W, u16* __restrict__ WT, int K, int N) {
  int i = blockIdx.x * blockDim.x + threadIdx.x;
  if (i >= K * N) return;
  int k = i / N, n = i - k * N;
  WT[n * K + k] = f2b(W[i]);
}

__global__ void to_bf16_kernel(const float* __restrict__ src, u16* __restrict__ dst, int n) {
  int i = (blockIdx.x * blockDim.x + threadIdx.x) * 4;
  if (i >= n) return;
  float4 v = *reinterpret_cast<const float4*>(src + i);
  us4 o;
  o.x = f2b(v.x); o.y = f2b(v.y); o.z = f2b(v.z); o.w = f2b(v.w);
  *reinterpret_cast<us4*>(dst + i) = o;
}

// d = bne @ Wen + ben
__global__ void dvec_kernel(const float* __restrict__ bne, const float* __restrict__ Wen,
                            const float* __restrict__ ben, float* __restrict__ d) {
  const int j = threadIdx.x;
  float s = ben[j];
  for (int k = 0; k < LATD; ++k) s += bne[k] * Wen[k * LATD + j];
  d[j] = s;
}

// ---------------- edge segment mean (4-deep pipelined gather) ----------------
// FP8SRC=1: fp8 rows (256B), 16-lane groups. FP8SRC=0: bf16 rows (512B), 32-lane.

template <int FP8SRC>
__global__ __launch_bounds__(256) void agg_kernel(const void* __restrict__ src,
                                                  const int* __restrict__ off,
                                                  const int* __restrict__ lst,
                                                  const float* __restrict__ recip,
                                                  u16* __restrict__ dst, int nseg) {
  constexpr int GW = FP8SRC ? 16 : 32;
  constexpr int EPL = LATD / GW;  // 16 or 8
  const int t = threadIdx.x;
  const int gl = t & (GW - 1);
  const int seg = blockIdx.x * (256 / GW) + (t / GW);
  if (seg >= nseg) return;
  const int s = off[seg], e = off[seg + 1];
  float a[EPL] = {};
  int p = s;
  if constexpr (FP8SRC) {
    for (; p + 4 <= e; p += 4) {
      const int r0 = lst[p], r1 = lst[p + 1], r2 = lst[p + 2], r3 = lst[p + 3];
      const u32x4 w0 = *(const u32x4*)((const u8*)src + (size_t)r0 * LATD + gl * 16);
      const u32x4 w1 = *(const u32x4*)((const u8*)src + (size_t)r1 * LATD + gl * 16);
      const u32x4 w2 = *(const u32x4*)((const u8*)src + (size_t)r2 * LATD + gl * 16);
      const u32x4 w3 = *(const u32x4*)((const u8*)src + (size_t)r3 * LATD + gl * 16);
      float f[16];
      fp8_dec16(w0, f);
#pragma unroll
      for (int j = 0; j < 16; ++j) a[j] += f[j];
      fp8_dec16(w1, f);
#pragma unroll
      for (int j = 0; j < 16; ++j) a[j] += f[j];
      fp8_dec16(w2, f);
#pragma unroll
      for (int j = 0; j < 16; ++j) a[j] += f[j];
      fp8_dec16(w3, f);
#pragma unroll
      for (int j = 0; j < 16; ++j) a[j] += f[j];
    }
    for (; p < e; ++p) {
      const u32x4 w = *(const u32x4*)((const u8*)src + (size_t)lst[p] * LATD + gl * 16);
      float f[16];
      fp8_dec16(w, f);
#pragma unroll
      for (int j = 0; j < 16; ++j) a[j] += f[j];
    }
  } else {
    for (; p + 4 <= e; p += 4) {
      const int r0 = lst[p], r1 = lst[p + 1], r2 = lst[p + 2], r3 = lst[p + 3];
      const us8 v0 = *(const us8*)((const u16*)src + (size_t)r0 * LATD + gl * 8);
      const us8 v1 = *(const us8*)((const u16*)src + (size_t)r1 * LATD + gl * 8);
      const us8 v2 = *(const us8*)((const u16*)src + (size_t)r2 * LATD + gl * 8);
      const us8 v3 = *(const us8*)((const u16*)src + (size_t)r3 * LATD + gl * 8);
#pragma unroll
      for (int j = 0; j < 8; ++j)
        a[j] += b2f(v0[j]) + b2f(v1[j]) + b2f(v2[j]) + b2f(v3[j]);
    }
    for (; p < e; ++p) {
      const us8 v = *(const us8*)((const u16*)src + (size_t)lst[p] * LATD + gl * 8);
#pragma unroll
      for (int j = 0; j < 8; ++j) a[j] += b2f(v[j]);
    }
  }
  const float rc = recip[seg];
  const size_t base = (size_t)seg * LATD + gl * EPL;
  if constexpr (FP8SRC) {
    us16 o;
#pragma unroll
    for (int j = 0; j < 16; ++j) o[j] = f2b(a[j] * rc);
    *(us16*)(dst + base) = o;
  } else {
    us8 o;
#pragma unroll
    for (int j = 0; j < 8; ++j) o[j] = f2b(a[j] * rc);
    *(us8*)(dst + base) = o;
  }
}

// ---------------- fused node-gather + RK epilogue ----------------
// STAGE 0 (bf16 G, 32-lane): u = mean + d; write ub(bf16), kout8 = fp8(k1)
// STAGE 1 (fp8 G, 16-lane):  k_i = tanh(u + c*mean); write kout8 only
// STAGE 3 (fp8 G, 16-lane):  k1 = tanh(u); k4 = tanh(u + c*mean);
//                            z += dt/6*(k1 + 2*dec(k2s) + 2*dec(k3s) + k4)

template <int STAGE>
__global__ __launch_bounds__(256) void aggn_epi_kernel(
    const void* __restrict__ G, const int* __restrict__ off, const int* __restrict__ lst,
    const float* __restrict__ recip, const float* __restrict__ dvec,
    u16* __restrict__ ub, const u8* __restrict__ k2s, const u8* __restrict__ k3s,
    u8* __restrict__ kout8, u16* __restrict__ zhi, float c) {
  constexpr int GW = (STAGE == 0) ? 32 : 16;
  constexpr int EPL = LATD / GW;  // 8 or 16
  const int t = threadIdx.x;
  const int gl = t & (GW - 1);
  const int node = blockIdx.x * (256 / GW) + (t / GW);
  if (node >= NN) return;
  const int s = off[node], e = off[node + 1];
  float v[EPL] = {};
  int p = s;
  if constexpr (STAGE == 0) {
    for (; p + 2 <= e; p += 2) {
      const int r0 = lst[p], r1 = lst[p + 1];
      const us8 g0 = *(const us8*)((const u16*)G + (size_t)r0 * LATD + gl * 8);
      const us8 g1 = *(const us8*)((const u16*)G + (size_t)r1 * LATD + gl * 8);
#pragma unroll
      for (int j = 0; j < 8; ++j) v[j] += b2f(g0[j]) + b2f(g1[j]);
    }
    for (; p < e; ++p) {
      const us8 g = *(const us8*)((const u16*)G + (size_t)lst[p] * LATD + gl * 8);
#pragma unroll
      for (int j = 0; j < 8; ++j) v[j] += b2f(g[j]);
    }
  } else {
    for (; p + 2 <= e; p += 2) {
      const int r0 = lst[p], r1 = lst[p + 1];
      const u32x4 w0 = *(const u32x4*)((const u8*)G + (size_t)r0 * LATD + gl * 16);
      const u32x4 w1 = *(const u32x4*)((const u8*)G + (size_t)r1 * LATD + gl * 16);
      float f[16];
      fp8_dec16(w0, f);
#pragma unroll
      for (int j = 0; j < 16; ++j) v[j] += f[j];
      fp8_dec16(w1, f);
#pragma unroll
      for (int j = 0; j < 16; ++j) v[j] += f[j];
    }
    for (; p < e; ++p) {
      const u32x4 w = *(const u32x4*)((const u8*)G + (size_t)lst[p] * LATD + gl * 16);
      float f[16];
      fp8_dec16(w, f);
#pragma unroll
      for (int j = 0; j < 16; ++j) v[j] += f[j];
    }
  }
  const float rc = recip[node];
  const size_t base = (size_t)node * LATD + gl * EPL;
  const float dt6 = 0.125f / 6.0f;

  if constexpr (STAGE == 0) {
    float kv[8];
    us8 uo;
#pragma unroll
    for (int j = 0; j < 8; ++j) {
      const float u = v[j] * rc + dvec[gl * 8 + j];
      uo[j] = f2b(u);
      kv[j] = fast_tanh(u);
    }
    *(us8*)(ub + base) = uo;
    u32x2 kp;
    kp[0] = fp8_enc4(kv);
    kp[1] = fp8_enc4(kv + 4);
    *(u32x2*)(kout8 + base) = kp;
  } else if constexpr (STAGE == 1) {
    const us16 uv = *(const us16*)(ub + base);
    float kv[16];
#pragma unroll
    for (int j = 0; j < 16; ++j)
      kv[j] = fast_tanh(b2f(uv[j]) + c * (v[j] * rc));
    u32x4 kp;
#pragma unroll
    for (int q = 0; q < 4; ++q) kp[q] = fp8_enc4(kv + q * 4);
    *(u32x4*)(kout8 + base) = kp;
  } else {  // STAGE 3
    const us16 uv = *(const us16*)(ub + base);
    const u32x4 w2 = *(const u32x4*)(k2s + base);
    const u32x4 w3 = *(const u32x4*)(k3s + base);
    const us16 zh = *(const us16*)(zhi + base);
    float f2[16], f3[16];
    fp8_dec16(w2, f2);
    fp8_dec16(w3, f3);
    us16 ho;
#pragma unroll
    for (int j = 0; j < 16; ++j) {
      const float u = b2f(uv[j]);
      const float k1 = fast_tanh(u);
      const float k4 = fast_tanh(u + c * (v[j] * rc));
      const float zn = b2f(zh[j]) + dt6 * (k1 + 2.0f * f2[j] + 2.0f * f3[j] + k4);
      ho[j] = f2b(zn);
    }
    *(us16*)(zhi + base) = ho;
  }
}

// ---------------- MFMA GEMM with LDS-staged coalesced epilogue ----------------

enum { EPI_RELU_BF16, EPI_BF16, EPI_F32, EPI_FP8 };

template <int MODE>
__global__ __launch_bounds__(256) void gemm_kernel(
    const u16* __restrict__ A, const u16* __restrict__ BT, const float* __restrict__ bias,
    int M, int N, int K,
    u16* __restrict__ outb, u8* __restrict__ outf8, float* __restrict__ outf) {
  __shared__ char smem[4 * 16 * 66 * 4];  // 16896B; GEMM phase uses first 16KB
  u16* lA = (u16*)smem;
  u16* lB = (u16*)(smem + 8192);
  const int t = threadIdx.x;
  const int m0 = blockIdx.x * 128, n0 = blockIdx.y * 128;
  const int srow = t >> 2;
  const int gslot = (t & 3) ^ ((srow >> 1) & 3);

  int ar0 = m0 + srow;      if (ar0 > M - 1) ar0 = M - 1;
  int ar1 = m0 + srow + 64; if (ar1 > M - 1) ar1 = M - 1;
  const u16* gA0 = A + (size_t)ar0 * K + gslot * 8;
  const u16* gA1 = A + (size_t)ar1 * K + gslot * 8;
  const u16* gB0 = BT + (size_t)(n0 + srow) * K + gslot * 8;
  const u16* gB1 = BT + (size_t)(n0 + srow + 64) * K + gslot * 8;
  char* lAd0 = (char*)lA + t * 16; char* lAd1 = lAd0 + 4096;
  char* lBd0 = (char*)lB + t * 16; char* lBd1 = lBd0 + 4096;

  const int lane = t & 63, wid = t >> 6;
  const int wm = wid >> 1, wn = wid & 1;
  const int lrow = lane & 15, kg = lane >> 4;

  f32x4 acc[4][4] = {};
  const char* lAb = (const char*)lA;
  const char* lBb = (const char*)lB;

  for (int kk = 0; kk < K; kk += 32) {
    async16(gA0 + kk, lAd0);
    async16(gA1 + kk, lAd1);
    async16(gB0 + kk, lBd0);
    async16(gB1 + kk, lBd1);
    __syncthreads();
    bf16x8 af[4], bg[4];
#pragma unroll
    for (int i = 0; i < 4; ++i) {
      int rA = wm * 64 + i * 16 + lrow;
      af[i] = *(const bf16x8*)(lAb + rA * 64 + (((kg ^ (rA >> 1)) & 3) << 4));
      int rB = wn * 64 + i * 16 + lrow;
      bg[i] = *(const bf16x8*)(lBb + rB * 64 + (((kg ^ (rB >> 1)) & 3) << 4));
    }
#pragma unroll
    for (int i = 0; i < 4; ++i)
#pragma unroll
      for (int j = 0; j < 4; ++j)
        acc[i][j] = __builtin_amdgcn_mfma_f32_16x16x32_bf16(af[i], bg[j], acc[i][j], 0, 0, 0);
    __syncthreads();
  }

  // staged epilogue (wave-private LDS region)
  float* stage = (float*)smem + wid * (16 * 66);
  const int rr = lane >> 3;
  const int c0 = (lane & 7) * 8;

#pragma unroll
  for (int ti = 0; ti < 4; ++ti) {
#pragma unroll
    for (int tj = 0; tj < 4; ++tj) {
      const float bv = bias[n0 + wn * 64 + tj * 16 + lrow];
#pragma unroll
      for (int j = 0; j < 4; ++j)
        stage[(kg * 4 + j) * 66 + tj * 16 + lrow] = acc[ti][tj][j] + bv;
    }
#pragma unroll
    for (int pass = 0; pass < 2; ++pass) {
      const int r = pass * 8 + rr;
      const int gr = m0 + wm * 64 + ti * 16 + r;
      if (gr >= M) continue;
      const int gc = n0 + wn * 64 + c0;
      const size_t idx = (size_t)gr * N + gc;
      float v[8];
      *(float4*)v = *(const float4*)&stage[r * 66 + c0];
      *(float4*)(v + 4) = *(const float4*)&stage[r * 66 + c0 + 4];

      if constexpr (MODE == EPI_RELU_BF16 || MODE == EPI_BF16) {
        us8 o;
#pragma unroll
        for (int e2 = 0; e2 < 8; ++e2)
          o[e2] = f2b(MODE == EPI_RELU_BF16 ? fmaxf(v[e2], 0.0f) : v[e2]);
        *(us8*)(outb + idx) = o;
      } else if constexpr (MODE == EPI_F32) {
        *(float4*)(outf + idx) = *(float4*)v;
        *(float4*)(outf + idx + 4) = *(float4*)(v + 4);
      } else {  // EPI_FP8
        u32x2 kp;
        kp[0] = fp8_enc4(v);
        kp[1] = fp8_enc4(v + 4);
        *(u32x2*)(outf8 + idx) = kp;
      }
    }
  }
}

// ---------------- launch ----------------

extern "C" void kernel_launch(void* const* d_in, const int* in_sizes, int n_in,
                              void* d_out, int out_size, void* d_ws, size_t ws_size,
                              hipStream_t stream) {
  const float* X = (const float*)d_in[0];
  const float* encW0 = (const float*)d_in[1];
  const float* encb0 = (const float*)d_in[2];
  const float* encW1 = (const float*)d_in[3];
  const float* encb1 = (const float*)d_in[4];
  const float* Wne = (const float*)d_in[5];
  const float* bne = (const float*)d_in[6];
  const float* Wen = (const float*)d_in[7];
  const float* ben = (const float*)d_in[8];
  const float* decW0 = (const float*)d_in[9];
  const float* decb0 = (const float*)d_in[10];
  const float* decW1 = (const float*)d_in[11];
  const float* decb1 = (const float*)d_in[12];
  const int* node_idx = (const int*)d_in[13];
  const int* edge_idx = (const int*)d_in[14];
  float* out = (float*)d_out;

  char* p = (char*)d_ws;
  auto alloc = [&](size_t bytes) {
    char* r = p;
    p += (bytes + 255) & ~(size_t)255;
    return r;
  };
  u16* zhi      = (u16*)alloc((size_t)NN * LATD * 2);
  u16* ub       = (u16*)alloc((size_t)NN * LATD * 2);
  u16* h1b      = (u16*)alloc((size_t)NN * LATD * 2);   // encode/decode hidden
  u8*  pA       = (u8*)alloc((size_t)NN * LATD);        // fp8 k plane A / bf16(X) scratch
  u8*  pB       = (u8*)alloc((size_t)NN * LATD);        // fp8 k plane B
  u16* eagg     = (u16*)alloc((size_t)NE * LATD * 2);
  u16* Gb       = (u16*)alloc((size_t)NE * LATD * 2);   // stage-0 G (bf16)
  u8*  Gf8      = (u8*)alloc((size_t)NE * LATD);        // stage-1..3 G (fp8)
  u16* encW0T   = (u16*)alloc((size_t)OBSD * LATD * 2);
  u16* encW1T   = (u16*)alloc((size_t)LATD * LATD * 2);
  u16* WneB     = (u16*)alloc((size_t)LATD * LATD * 2);
  u16* WenT     = (u16*)alloc((size_t)LATD * LATD * 2);
  u16* WcT      = (u16*)alloc((size_t)LATD * LATD * 2);
  u16* decW0T   = (u16*)alloc((size_t)LATD * LATD * 2);
  u16* decW1T   = (u16*)alloc((size_t)LATD * OBSD * 2);
  float* dvec   = (float*)alloc(LATD * 4);
  float* zeros  = (float*)alloc(LATD * 4);
  int* cnt      = (int*)alloc((size_t)(NE + NN) * 4);
  int* cnt_e = cnt; int* cnt_n = cnt + NE;
  int* off_e    = (int*)alloc((size_t)(NE + 1) * 4);
  int* off_n    = (int*)alloc((size_t)(NN + 1) * 4);
  int* cur_e    = (int*)alloc((size_t)NE * 4);
  int* cur_n    = (int*)alloc((size_t)NN * 4);
  int* lst_e    = (int*)alloc((size_t)NNZC * 4);
  int* lst_n    = (int*)alloc((size_t)NNZC * 4);
  float* recip_e = (float*)alloc((size_t)NE * 4);
  float* recip_n = (float*)alloc((size_t)NN * 4);
  int* bsum_e   = (int*)alloc(16 * 4);
  int* bsum_n   = (int*)alloc(64 * 4);

  size_t needed = (size_t)(p - (char*)d_ws);
  if (needed > ws_size) {
    hipMemsetAsync(d_out, 0x7F, (size_t)out_size * 4, stream);
    return;
  }

  const int nbe = (NE + 1023) / 1024, nbn = (NN + 1023) / 1024;

  // CSR build
  hipMemsetAsync(cnt, 0, (size_t)(NE + NN) * 4, stream);
  count_kernel<<<(NNZC + 255) / 256, 256, 0, stream>>>(node_idx, edge_idx, cnt_n, cnt_e, NNZC);
  scan1_kernel<<<nbe, 1024, 0, stream>>>(cnt_e, off_e, bsum_e, NE);
  scan1_kernel<<<nbn, 1024, 0, stream>>>(cnt_n, off_n, bsum_n, NN);
  scan2_kernel<<<1, 64, 0, stream>>>(bsum_e, nbe);
  scan2_kernel<<<1, 64, 0, stream>>>(bsum_n, nbn);
  scan3_kernel<<<(NE + 255) / 256, 256, 0, stream>>>(cnt_e, off_e, cur_e, recip_e, bsum_e, NE);
  scan3_kernel<<<(NN + 255) / 256, 256, 0, stream>>>(cnt_n, off_n, cur_n, recip_n, bsum_n, NN);
  fill_kernel<<<(NNZC + 255) / 256, 256, 0, stream>>>(node_idx, edge_idx, cur_n, cur_e, lst_n, lst_e, NNZC);

  // weight prep
  transpose_kernel<<<(OBSD * LATD + 255) / 256, 256, 0, stream>>>(encW0, encW0T, OBSD, LATD);
  transpose_kernel<<<(LATD * LATD + 255) / 256, 256, 0, stream>>>(encW1, encW1T, LATD, LATD);
  transpose_kernel<<<(LATD * LATD + 255) / 256, 256, 0, stream>>>(Wen, WenT, LATD, LATD);
  transpose_kernel<<<(LATD * LATD + 255) / 256, 256, 0, stream>>>(decW0, decW0T, LATD, LATD);
  transpose_kernel<<<(LATD * OBSD + 255) / 256, 256, 0, stream>>>(decW1, decW1T, LATD, OBSD);
  to_bf16_kernel<<<(LATD * LATD / 4 + 255) / 256, 256, 0, stream>>>(Wne, WneB, LATD * LATD);
  hipMemsetAsync(zeros, 0, LATD * 4, stream);
  dvec_kernel<<<1, LATD, 0, stream>>>(bne, Wen, ben, dvec);
  gemm_kernel<EPI_BF16><<<dim3(2, 2), 256, 0, stream>>>(WenT, WneB, zeros, LATD, LATD, LATD,
                                                        WcT, nullptr, nullptr);

  const dim3 blk(256);
  const dim3 g50((NN + 127) / 128, LATD / 128);   // (391, 2)
  const dim3 g10((NE + 127) / 128, LATD / 128);   // (79, 2)
  const dim3 gdec((NN + 127) / 128, OBSD / 128);  // (391, 1)
  const dim3 gae32((NE + 7) / 8);                 // 1250 (bf16 src)
  const dim3 gae16((NE + 15) / 16);               // 625  (fp8 src)
  const dim3 gan32((NN + 7) / 8);                 // 6250 (stage 0)
  const dim3 gan16((NN + 15) / 16);               // 3125 (stages 1-3)

  // encode: h1 = relu(X@W0+b0) ; z = h1@W1+b1 -> zhi (bf16)
  to_bf16_kernel<<<(NN * OBSD / 4 + 255) / 256, 256, 0, stream>>>(X, (u16*)pA, NN * OBSD);
  gemm_kernel<EPI_RELU_BF16><<<g50, blk, 0, stream>>>((u16*)pA, encW0T, encb0, NN, LATD, OBSD,
                                                      h1b, nullptr, nullptr);
  gemm_kernel<EPI_BF16><<<g50, blk, 0, stream>>>(h1b, encW1T, encb1, NN, LATD, LATD,
                                                 zhi, nullptr, nullptr);

  // RK4: per substep  agg_e -> edge GEMM (Wc) -> fused node-gather+epilogue
  // fp8 k planes ping-pong: k1->pA, k2->pB, k3->pA; stage3 reads k2=pB, k3=pA
  for (int s = 0; s < NSTEPS; ++s) {
    // k=0
    agg_kernel<0><<<gae32, blk, 0, stream>>>(zhi, off_e, lst_e, recip_e, eagg, NE);
    gemm_kernel<EPI_BF16><<<g10, blk, 0, stream>>>(eagg, WcT, zeros, NE, LATD, LATD,
                                                   Gb, nullptr, nullptr);
    aggn_epi_kernel<0><<<gan32, blk, 0, stream>>>(Gb, off_n, lst_n, recip_n, dvec,
                                                  ub, nullptr, nullptr, pA, zhi, 0.f);
    // k=1
    agg_kernel<1><<<gae16, blk, 0, stream>>>(pA, off_e, lst_e, recip_e, eagg, NE);
    gemm_kernel<EPI_FP8><<<g10, blk, 0, stream>>>(eagg, WcT, zeros, NE, LATD, LATD,
                                                  nullptr, Gf8, nullptr);
    aggn_epi_kernel<1><<<gan16, blk, 0, stream>>>(Gf8, off_n, lst_n, recip_n, dvec,
                                                  ub, nullptr, nullptr, pB, zhi, 0.0625f);
    // k=2
    agg_kernel<1><<<gae16, blk, 0, stream>>>(pB, off_e, lst_e, recip_e, eagg, NE);
    gemm_kernel<EPI_FP8><<<g10, blk, 0, stream>>>(eagg, WcT, zeros, NE, LATD, LATD,
                                                  nullptr, Gf8, nullptr);
    aggn_epi_kernel<1><<<gan16, blk, 0, stream>>>(Gf8, off_n, lst_n, recip_n, dvec,
                                                  ub, nullptr, nullptr, pA, zhi, 0.0625f);
    // k=3
    agg_kernel<1><<<gae16, blk, 0, stream>>>(pA, off_e, lst_e, recip_e, eagg, NE);
    gemm_kernel<EPI_FP8><<<g10, blk, 0, stream>>>(eagg, WcT, zeros, NE, LATD, LATD,
                                                  nullptr, Gf8, nullptr);
    aggn_epi_kernel<3><<<gan16, blk, 0, stream>>>(Gf8, off_n, lst_n, recip_n, dvec,
                                                  ub, pB, pA, nullptr, zhi, 0.125f);
  }

  // decode (zhi = bf16(z_final))
  gemm_kernel<EPI_RELU_BF16><<<g50, blk, 0, stream>>>(zhi, decW0T, decb0, NN, LATD, LATD,
                                                      h1b, nullptr, nullptr);
  gemm_kernel<EPI_F32><<<gdec, blk, 0, stream>>>(h1b, decW1T, decb1, NN, OBSD, LATD,
                                                 nullptr, nullptr, out);
}